// Round 2
// baseline (562.053 us; speedup 1.0000x reference)
//
#include <hip/hip_runtime.h>
#include <hip/hip_bf16.h>
#include <math.h>

#define HH 512
#define NVARS 16384
#define NPOS 4096
#define NMS 4096
#define NEGV -1.0e30f
#define RSQRT_H 0.04419417382415922f   // 1/sqrt(512)

#define BM 128
#define BK 16

struct SPart { float m; float s; int a; int pad; };

__device__ inline void wreduce_maxidx(float& v, int& idx) {
#pragma unroll
  for (int m = 1; m < 64; m <<= 1) {
    float ov = __shfl_xor(v, m, 64);
    int oi = __shfl_xor(idx, m, 64);
    if (ov > v || (ov == v && oi < idx)) { v = ov; idx = oi; }
  }
}

__device__ inline float wreduce_sum(float v) {
#pragma unroll
  for (int m = 1; m < 64; m <<= 1) v += __shfl_xor(v, m, 64);
  return v;
}

// ---------------------------------------------------------------------------
// Mask format detection: int32 masks have all words in {0,1}; bool-byte masks
// have 4 packed 0/1 bytes per word (word > 1 with prob 7/8 per word).
__global__ void detect_kernel(const unsigned int* __restrict__ keep, int* __restrict__ flag) {
  if (threadIdx.x == 0 && blockIdx.x == 0) {
    int ok = 1;
    for (int i = 0; i < 64; ++i) if (keep[i] > 1u) ok = 0;
    *flag = ok;   // 1: int32 masks, 0: byte masks
  }
}

// Pack valid = keep & ~taken into bitmask words: vmask[row*64 + col/64], bit = col%64.
__global__ __launch_bounds__(256) void pack_kernel(
    const void* __restrict__ keep, const void* __restrict__ taken,
    const int* __restrict__ flag, unsigned long long* __restrict__ vmask) {
  const int f = *flag;
  const int t = threadIdx.x;
#pragma unroll
  for (int it = 0; it < 4; ++it) {
    size_t e = (size_t)blockIdx.x * 1024 + (size_t)it * 256 + t;
    int kv, tv;
    if (f) {
      kv = ((const int*)keep)[e];
      tv = ((const int*)taken)[e];
    } else {
      kv = ((const unsigned char*)keep)[e];
      tv = ((const unsigned char*)taken)[e];
    }
    unsigned long long m = __ballot(kv != 0 && tv == 0);
    if ((t & 63) == 0) vmask[e >> 6] = m;
  }
}

// ---------------------------------------------------------------------------
// Q = sum over clause rows; 512 blocks x 128 rows, f64 partials for precision
// (Q feeds tanh saturation boundaries that decide the var_idx argmax).
__global__ __launch_bounds__(256) void qsum_kernel(
    const float* __restrict__ clause, double* __restrict__ qpart) {
  const int b = blockIdx.x, t = threadIdx.x;
  const float* base = clause + (size_t)b * 128 * HH;
  double a0 = 0.0, a1 = 0.0;
#pragma unroll 4
  for (int r = 0; r < 128; ++r) {
    a0 += (double)base[(size_t)r * HH + t];
    a1 += (double)base[(size_t)r * HH + t + 256];
  }
  qpart[b * HH + t] = a0;
  qpart[b * HH + t + 256] = a1;
}

// tvec[h] = (Q @ var_Q_w.T)[h] + var_Q_b[h] + var_K_b[h]  (f64 accumulation)
__global__ __launch_bounds__(512) void prep_kernel(
    const double* __restrict__ qpart, const float* __restrict__ varQw,
    const float* __restrict__ varQb, const float* __restrict__ varKb,
    float* __restrict__ tvec) {
  __shared__ double Q[HH];
  const int t = threadIdx.x;
  double s = 0.0;
  for (int b = 0; b < 512; ++b) s += qpart[b * HH + t];
  Q[t] = s;
  __syncthreads();
  const float* wrow = varQw + (size_t)t * HH;
  double acc = (double)varQb[t];
  for (int c = 0; c < HH; ++c) acc += Q[c] * (double)wrow[c];
  tvec[t] = (float)(acc + (double)varKb[t]);
}

// ---------------------------------------------------------------------------
// Shared tiled f32 NT-GEMM structure: C[i][j] = sum_c A[i][c]*B[j][c].
// 128x128 block tile, BK=16, 256 threads, 8x8 microtile as split quads.

#define GEMM_LOAD_TILE(APTR, AROWEXPR, BPTR, BROWEXPR)                               \
  _Pragma("unroll")                                                                  \
  for (int qq = 0; qq < 2; ++qq) {                                                   \
    int fidx = t * 2 + qq;                                                           \
    int r = fidx >> 2;                                                               \
    int jc = (fidx & 3) * 4;                                                         \
    int arow_ = (AROWEXPR);                                                          \
    float4 va = *(const float4*)((APTR) + (size_t)arow_ * HH + k0 + jc);             \
    As[jc + 0][r] = va.x; As[jc + 1][r] = va.y;                                      \
    As[jc + 2][r] = va.z; As[jc + 3][r] = va.w;                                      \
    int brow_ = (BROWEXPR);                                                          \
    float4 vb = *(const float4*)((BPTR) + (size_t)brow_ * HH + k0 + jc);             \
    Bs[jc + 0][r] = vb.x; Bs[jc + 1][r] = vb.y;                                      \
    Bs[jc + 2][r] = vb.z; Bs[jc + 3][r] = vb.w;                                      \
  }

#define GEMM_INNER                                                                   \
  _Pragma("unroll")                                                                  \
  for (int k = 0; k < BK; ++k) {                                                     \
    float av[8], bv[8];                                                              \
    *(float4*)&av[0] = *(const float4*)&As[k][ty * 4];                               \
    *(float4*)&av[4] = *(const float4*)&As[k][64 + ty * 4];                          \
    *(float4*)&bv[0] = *(const float4*)&Bs[k][tx * 4];                               \
    *(float4*)&bv[4] = *(const float4*)&Bs[k][64 + tx * 4];                          \
    _Pragma("unroll")                                                                \
    for (int i = 0; i < 8; ++i)                                                      \
      _Pragma("unroll")                                                              \
      for (int j = 0; j < 8; ++j)                                                    \
        acc[i][j] += av[i] * bv[j];                                                  \
  }

// q/k projection with row gather: out[n][h] = clause[idx[n]] @ W.T + b
__global__ __launch_bounds__(256) void proj_kernel(
    const float* __restrict__ clause,
    const int* __restrict__ pos_idx, const int* __restrict__ neg_idx,
    const float* __restrict__ WQ, const float* __restrict__ bQ,
    const float* __restrict__ WK, const float* __restrict__ bK,
    float* __restrict__ qmat, float* __restrict__ kmat) {
  const int* __restrict__ idx = blockIdx.z ? neg_idx : pos_idx;
  const float* __restrict__ W = blockIdx.z ? WK : WQ;
  const float* __restrict__ bias = blockIdx.z ? bK : bQ;
  float* __restrict__ out = blockIdx.z ? kmat : qmat;

  __shared__ float As[BK][BM];
  __shared__ float Bs[BK][BM];
  const int t = threadIdx.x;
  const int tx = t & 15, ty = t >> 4;
  const int row0 = blockIdx.x * BM;
  const int col0 = blockIdx.y * BM;
  float acc[8][8] = {};
  for (int k0 = 0; k0 < HH; k0 += BK) {
    GEMM_LOAD_TILE(clause, idx[row0 + r], W, col0 + r)
    __syncthreads();
    GEMM_INNER
    __syncthreads();
  }
#pragma unroll
  for (int i = 0; i < 8; ++i) {
    int rl = (i < 4) ? (ty * 4 + i) : (64 + ty * 4 + i - 4);
    size_t rbase = (size_t)(row0 + rl) * HH;
#pragma unroll
    for (int jh = 0; jh < 2; ++jh) {
      int c = col0 + jh * 64 + tx * 4;
      float4 o;
      o.x = acc[i][jh * 4 + 0] + bias[c + 0];
      o.y = acc[i][jh * 4 + 1] + bias[c + 1];
      o.z = acc[i][jh * 4 + 2] + bias[c + 2];
      o.w = acc[i][jh * 4 + 3] + bias[c + 3];
      *(float4*)(out + rbase + c) = o;
    }
  }
}

// K_t GEMM fused with tanh epilogue -> u partials (per h-block).
__global__ __launch_bounds__(256) void ktu_kernel(
    const float* __restrict__ lit, const float* __restrict__ varKw,
    const float* __restrict__ tvec, const float* __restrict__ attnw,
    float* __restrict__ upart) {
  __shared__ float As[BK][BM];
  __shared__ float Bs[BK][BM];
  __shared__ float s_t[BM], s_a[BM];
  const int t = threadIdx.x;
  const int tx = t & 15, ty = t >> 4;
  const int row0 = blockIdx.x * BM;
  const int col0 = blockIdx.y * BM;
  if (t < BM) { s_t[t] = tvec[col0 + t]; s_a[t] = attnw[col0 + t]; }
  float acc[8][8] = {};
  for (int k0 = 0; k0 < HH; k0 += BK) {
    GEMM_LOAD_TILE(lit, row0 + r, varKw, col0 + r)
    __syncthreads();
    GEMM_INNER
    __syncthreads();
  }
  float us[8];
#pragma unroll
  for (int i = 0; i < 8; ++i) {
    float s = 0.f;
#pragma unroll
    for (int j = 0; j < 8; ++j) {
      int cl = (j < 4) ? (tx * 4 + j) : (64 + tx * 4 + j - 4);
      s += tanhf(acc[i][j] + s_t[cl]) * s_a[cl];
    }
    us[i] = s;
  }
#pragma unroll
  for (int m = 1; m < 16; m <<= 1) {
#pragma unroll
    for (int i = 0; i < 8; ++i) us[i] += __shfl_xor(us[i], m, 64);
  }
  if (tx == 0) {
#pragma unroll
    for (int i = 0; i < 8; ++i) {
      int rl = (i < 4) ? (ty * 4 + i) : (64 + ty * 4 + i - 4);
      upart[(size_t)blockIdx.y * NVARS + row0 + rl] = us[i];
    }
  }
}

// scores = q @ k.T / sqrt(H), masked; per-block {max, argmax, sumexp}.
__global__ __launch_bounds__(256) void scores_kernel(
    const float* __restrict__ qmat, const float* __restrict__ kmat,
    const unsigned long long* __restrict__ vmask, SPart* __restrict__ parts) {
  __shared__ float As[BK][BM];
  __shared__ float Bs[BK][BM];
  __shared__ unsigned long long mrow[BM][2];
  __shared__ float s_rv[4]; __shared__ int s_ri[4]; __shared__ float s_rs[4];
  __shared__ float s_bm; __shared__ int s_ba;
  const int t = threadIdx.x;
  const int tx = t & 15, ty = t >> 4;
  const int n0 = blockIdx.y * BM;   // q rows
  const int m0 = blockIdx.x * BM;   // k rows
  float acc[8][8] = {};
  for (int k0 = 0; k0 < HH; k0 += BK) {
    GEMM_LOAD_TILE(qmat, n0 + r, kmat, m0 + r)
    __syncthreads();
    GEMM_INNER
    __syncthreads();
  }
  {
    int r = t >> 1, w = t & 1;
    mrow[r][w] = vmask[(size_t)(n0 + r) * (NMS / 64) + (m0 >> 6) + w];
  }
  __syncthreads();
  // phase 1: masked max + argmax (first-occurrence tie-break)
  float mv = NEGV; int mi = 0x7fffffff;
#pragma unroll
  for (int i = 0; i < 8; ++i) {
    int rl = (i < 4) ? (ty * 4 + i) : (64 + ty * 4 + i - 4);
    unsigned long long w0 = mrow[rl][0], w1 = mrow[rl][1];
    int gbase = (n0 + rl) * NMS + m0;
#pragma unroll
    for (int j = 0; j < 8; ++j) {
      float sv = acc[i][j] * RSQRT_H;
      acc[i][j] = sv;
      int bit = tx * 4 + (j & 3);
      bool valid = ((((j < 4) ? w0 : w1) >> bit) & 1ull) != 0;
      int cl = (j < 4) ? bit : (64 + bit);
      if (valid && (sv > mv || (sv == mv && gbase + cl < mi))) { mv = sv; mi = gbase + cl; }
    }
  }
  wreduce_maxidx(mv, mi);
  if ((t & 63) == 0) { s_rv[t >> 6] = mv; s_ri[t >> 6] = mi; }
  __syncthreads();
  if (t == 0) {
    float bm = s_rv[0]; int ba = s_ri[0];
    for (int w = 1; w < 4; ++w)
      if (s_rv[w] > bm || (s_rv[w] == bm && s_ri[w] < ba)) { bm = s_rv[w]; ba = s_ri[w]; }
    s_bm = bm; s_ba = ba;
  }
  __syncthreads();
  const float bm = s_bm;
  // phase 2: sum exp(s - blockmax) over valid
  float se = 0.f;
#pragma unroll
  for (int i = 0; i < 8; ++i) {
    int rl = (i < 4) ? (ty * 4 + i) : (64 + ty * 4 + i - 4);
    unsigned long long w0 = mrow[rl][0], w1 = mrow[rl][1];
#pragma unroll
    for (int j = 0; j < 8; ++j) {
      int bit = tx * 4 + (j & 3);
      bool valid = ((((j < 4) ? w0 : w1) >> bit) & 1ull) != 0;
      if (valid) se += __expf(acc[i][j] - bm);
    }
  }
  se = wreduce_sum(se);
  if ((t & 63) == 0) s_rs[t >> 6] = se;
  __syncthreads();
  if (t == 0) {
    SPart p;
    p.m = s_bm;
    p.s = s_rs[0] + s_rs[1] + s_rs[2] + s_rs[3];
    p.a = s_ba; p.pad = 0;
    parts[blockIdx.y * gridDim.x + blockIdx.x] = p;
  }
}

// Final combine: u reduction (max/argmax/lse) + score-part reduction + outputs.
// d_out is FLOAT32 x4: {c_logp, pos_idx[ci], neg_idx[cj], var_idx}.
__global__ __launch_bounds__(256) void final_kernel(
    const float* __restrict__ upart, const SPart* __restrict__ parts,
    const int* __restrict__ pos_idx, const int* __restrict__ neg_idx,
    float* __restrict__ out) {
  __shared__ float s_rv[4]; __shared__ int s_ri[4]; __shared__ float s_rs[4];
  __shared__ float s_umax; __shared__ int s_uarg; __shared__ float s_usum;
  __shared__ float s_gm; __shared__ int s_ga;
  const int t = threadIdx.x;

  // --- u = sum of 4 h-block partials ---
  float mv = -1.0e38f; int mi = 0x7fffffff;
  for (int i = t; i < NVARS; i += 256) {
    float u = upart[i] + upart[NVARS + i] + upart[2 * NVARS + i] + upart[3 * NVARS + i];
    if (u > mv || (u == mv && i < mi)) { mv = u; mi = i; }
  }
  wreduce_maxidx(mv, mi);
  if ((t & 63) == 0) { s_rv[t >> 6] = mv; s_ri[t >> 6] = mi; }
  __syncthreads();
  if (t == 0) {
    float bm = s_rv[0]; int ba = s_ri[0];
    for (int w = 1; w < 4; ++w)
      if (s_rv[w] > bm || (s_rv[w] == bm && s_ri[w] < ba)) { bm = s_rv[w]; ba = s_ri[w]; }
    s_umax = bm; s_uarg = ba;
  }
  __syncthreads();
  const float umax = s_umax;
  float se = 0.f;
  for (int i = t; i < NVARS; i += 256) {
    float u = upart[i] + upart[NVARS + i] + upart[2 * NVARS + i] + upart[3 * NVARS + i];
    se += __expf(u - umax);
  }
  se = wreduce_sum(se);
  if ((t & 63) == 0) s_rs[t >> 6] = se;
  __syncthreads();
  if (t == 0) s_usum = s_rs[0] + s_rs[1] + s_rs[2] + s_rs[3];
  __syncthreads();

  // --- score block partials ---
  mv = NEGV; mi = 0x7fffffff;
  for (int i = t; i < 1024; i += 256) {
    SPart p = parts[i];
    if (p.m > mv || (p.m == mv && p.a < mi)) { mv = p.m; mi = p.a; }
  }
  wreduce_maxidx(mv, mi);
  if ((t & 63) == 0) { s_rv[t >> 6] = mv; s_ri[t >> 6] = mi; }
  __syncthreads();
  if (t == 0) {
    float bm = s_rv[0]; int ba = s_ri[0];
    for (int w = 1; w < 4; ++w)
      if (s_rv[w] > bm || (s_rv[w] == bm && s_ri[w] < ba)) { bm = s_rv[w]; ba = s_ri[w]; }
    s_gm = bm; s_ga = ba;
  }
  __syncthreads();
  const float gm = s_gm;
  float ss = 0.f;
  for (int i = t; i < 1024; i += 256) {
    SPart p = parts[i];
    ss += p.s * __expf(p.m - gm);
  }
  ss = wreduce_sum(ss);
  if ((t & 63) == 0) s_rs[t >> 6] = ss;
  __syncthreads();
  if (t == 0) {
    float gsum = s_rs[0] + s_rs[1] + s_rs[2] + s_rs[3];
    float c_logp = -logf(gsum) - logf(s_usum);   // (maxS-lseS) + (maxU-lseU)
    int ga = s_ga;
    if (ga == 0x7fffffff) ga = 0;   // no valid element anywhere -> argmax 0 like ref
    int ci = ga >> 12, cj = ga & 4095;
    out[0] = c_logp;
    out[1] = (float)pos_idx[ci];
    out[2] = (float)neg_idx[cj];
    out[3] = (float)s_uarg;
  }
}

extern "C" void kernel_launch(void* const* d_in, const int* in_sizes, int n_in,
                              void* d_out, int out_size, void* d_ws, size_t ws_size,
                              hipStream_t stream) {
  (void)in_sizes; (void)n_in; (void)out_size; (void)ws_size;
  const float* lit    = (const float*)d_in[0];
  const float* clause = (const float*)d_in[1];
  const int* pos_idx  = (const int*)d_in[2];
  const int* neg_idx  = (const int*)d_in[3];
  const void* keep    = d_in[4];
  const void* taken   = d_in[5];
  const float* varKw  = (const float*)d_in[6];
  const float* varKb  = (const float*)d_in[7];
  const float* varQw  = (const float*)d_in[8];
  const float* varQb  = (const float*)d_in[9];
  const float* attnw  = (const float*)d_in[10];
  // d_in[11] var_attn_b: uniform shift, cancels in log_softmax max/argmax
  const float* WQw    = (const float*)d_in[12];
  const float* WQb    = (const float*)d_in[13];
  const float* WKw    = (const float*)d_in[14];
  const float* WKb    = (const float*)d_in[15];

  char* ws = (char*)d_ws;
  size_t off = 0;
  auto alloc = [&](size_t b) {
    char* p = ws + off;
    off = (off + b + 255) & ~(size_t)255;
    return p;
  };
  int* flag                  = (int*)alloc(4);
  double* qpart              = (double*)alloc((size_t)512 * HH * 8);
  float* tvec                = (float*)alloc(HH * 4);
  float* upart               = (float*)alloc(4 * (size_t)NVARS * 4);
  unsigned long long* vmask  = (unsigned long long*)alloc((size_t)NPOS * (NMS / 64) * 8);
  float* qmat                = (float*)alloc((size_t)NPOS * HH * 4);
  float* kmat                = (float*)alloc((size_t)NMS * HH * 4);
  SPart* parts               = (SPart*)alloc(1024 * sizeof(SPart));

  detect_kernel<<<1, 64, 0, stream>>>((const unsigned int*)keep, flag);
  pack_kernel<<<16384, 256, 0, stream>>>(keep, taken, flag, vmask);
  qsum_kernel<<<512, 256, 0, stream>>>(clause, qpart);
  prep_kernel<<<1, 512, 0, stream>>>(qpart, varQw, varQb, varKb, tvec);
  proj_kernel<<<dim3(32, 4, 2), 256, 0, stream>>>(clause, pos_idx, neg_idx,
                                                  WQw, WQb, WKw, WKb, qmat, kmat);
  ktu_kernel<<<dim3(128, 4), 256, 0, stream>>>(lit, varKw, tvec, attnw, upart);
  scores_kernel<<<dim3(32, 32), 256, 0, stream>>>(qmat, kmat, vmask, parts);
  final_kernel<<<1, 256, 0, stream>>>(upart, parts, pos_idx, neg_idx,
                                      (float*)d_out);
}

// Round 3
// 504.333 us; speedup vs baseline: 1.1144x; 1.1144x over previous
//
#include <hip/hip_runtime.h>
#include <hip/hip_bf16.h>
#include <math.h>

#define HH 512
#define NVARS 16384
#define NPOS 4096
#define NMS 4096
#define NEGV -1.0e30f
#define RSQRT_H 0.04419417382415922f   // 1/sqrt(512)

#define BM 128
#define BK 16

typedef unsigned short u16;
typedef __attribute__((ext_vector_type(8))) short bf16x8;
typedef __attribute__((ext_vector_type(4))) float f32x4;

struct SPart { float m; float s; int a; int pad; };

__device__ inline u16 f2bf(float f) {
  unsigned u = __float_as_uint(f);
  unsigned r = (u + 0x7fffu + ((u >> 16) & 1u)) >> 16;
  return (u16)r;
}
__device__ inline float bf2f(u16 h) { return __uint_as_float(((unsigned)h) << 16); }

__device__ inline void wreduce_maxidx(float& v, int& idx) {
#pragma unroll
  for (int m = 1; m < 64; m <<= 1) {
    float ov = __shfl_xor(v, m, 64);
    int oi = __shfl_xor(idx, m, 64);
    if (ov > v || (ov == v && oi < idx)) { v = ov; idx = oi; }
  }
}

__device__ inline float wreduce_sum(float v) {
#pragma unroll
  for (int m = 1; m < 64; m <<= 1) v += __shfl_xor(v, m, 64);
  return v;
}

// ---------------------------------------------------------------------------
__global__ void detect_kernel(const unsigned int* __restrict__ keep, int* __restrict__ flag) {
  if (threadIdx.x == 0 && blockIdx.x == 0) {
    int ok = 1;
    for (int i = 0; i < 64; ++i) if (keep[i] > 1u) ok = 0;
    *flag = ok;   // 1: int32 masks, 0: byte masks
  }
}

__global__ __launch_bounds__(256) void pack_kernel(
    const void* __restrict__ keep, const void* __restrict__ taken,
    const int* __restrict__ flag, unsigned long long* __restrict__ vmask) {
  const int f = *flag;
  const int t = threadIdx.x;
#pragma unroll
  for (int it = 0; it < 4; ++it) {
    size_t e = (size_t)blockIdx.x * 1024 + (size_t)it * 256 + t;
    int kv, tv;
    if (f) {
      kv = ((const int*)keep)[e];
      tv = ((const int*)taken)[e];
    } else {
      kv = ((const unsigned char*)keep)[e];
      tv = ((const unsigned char*)taken)[e];
    }
    unsigned long long m = __ballot(kv != 0 && tv == 0);
    if ((t & 63) == 0) vmask[e >> 6] = m;
  }
}

// ---------------------------------------------------------------------------
__global__ __launch_bounds__(256) void qsum_kernel(
    const float* __restrict__ clause, double* __restrict__ qpart) {
  const int b = blockIdx.x, t = threadIdx.x;
  const float* base = clause + (size_t)b * 128 * HH;
  double a0 = 0.0, a1 = 0.0;
#pragma unroll 4
  for (int r = 0; r < 128; ++r) {
    a0 += (double)base[(size_t)r * HH + t];
    a1 += (double)base[(size_t)r * HH + t + 256];
  }
  qpart[b * HH + t] = a0;
  qpart[b * HH + t + 256] = a1;
}

__global__ __launch_bounds__(512) void prep_kernel(
    const double* __restrict__ qpart, const float* __restrict__ varQw,
    const float* __restrict__ varQb, const float* __restrict__ varKb,
    float* __restrict__ tvec) {
  __shared__ double Q[HH];
  const int t = threadIdx.x;
  double s = 0.0;
  for (int b = 0; b < 512; ++b) s += qpart[b * HH + t];
  Q[t] = s;
  __syncthreads();
  const float* wrow = varQw + (size_t)t * HH;
  double acc = (double)varQb[t];
  for (int c = 0; c < HH; ++c) acc += Q[c] * (double)wrow[c];
  tvec[t] = (float)(acc + (double)varKb[t]);
}

// ---------------------------------------------------------------------------
// f32 tiled NT-GEMM pieces (still used by proj/ktu this round)

#define GEMM_LOAD_TILE(APTR, AROWEXPR, BPTR, BROWEXPR)                               \
  _Pragma("unroll")                                                                  \
  for (int qq = 0; qq < 2; ++qq) {                                                   \
    int fidx = t * 2 + qq;                                                           \
    int r = fidx >> 2;                                                               \
    int jc = (fidx & 3) * 4;                                                         \
    int arow_ = (AROWEXPR);                                                          \
    float4 va = *(const float4*)((APTR) + (size_t)arow_ * HH + k0 + jc);             \
    As[jc + 0][r] = va.x; As[jc + 1][r] = va.y;                                      \
    As[jc + 2][r] = va.z; As[jc + 3][r] = va.w;                                      \
    int brow_ = (BROWEXPR);                                                          \
    float4 vb = *(const float4*)((BPTR) + (size_t)brow_ * HH + k0 + jc);             \
    Bs[jc + 0][r] = vb.x; Bs[jc + 1][r] = vb.y;                                      \
    Bs[jc + 2][r] = vb.z; Bs[jc + 3][r] = vb.w;                                      \
  }

#define GEMM_INNER                                                                   \
  _Pragma("unroll")                                                                  \
  for (int k = 0; k < BK; ++k) {                                                     \
    float av[8], bv[8];                                                              \
    *(float4*)&av[0] = *(const float4*)&As[k][ty * 4];                               \
    *(float4*)&av[4] = *(const float4*)&As[k][64 + ty * 4];                          \
    *(float4*)&bv[0] = *(const float4*)&Bs[k][tx * 4];                               \
    *(float4*)&bv[4] = *(const float4*)&Bs[k][64 + tx * 4];                          \
    _Pragma("unroll")                                                                \
    for (int i = 0; i < 8; ++i)                                                      \
      _Pragma("unroll")                                                              \
      for (int j = 0; j < 8; ++j)                                                    \
        acc[i][j] += av[i] * bv[j];                                                  \
  }

// q/k projection with row gather; epilogue emits bf16 hi/lo split arrays.
__global__ __launch_bounds__(256) void proj_kernel(
    const float* __restrict__ clause,
    const int* __restrict__ pos_idx, const int* __restrict__ neg_idx,
    const float* __restrict__ WQ, const float* __restrict__ bQ,
    const float* __restrict__ WK, const float* __restrict__ bK,
    u16* __restrict__ qhi, u16* __restrict__ qlo,
    u16* __restrict__ khi, u16* __restrict__ klo) {
  const int* __restrict__ idx = blockIdx.z ? neg_idx : pos_idx;
  const float* __restrict__ W = blockIdx.z ? WK : WQ;
  const float* __restrict__ bias = blockIdx.z ? bK : bQ;
  u16* __restrict__ ohi = blockIdx.z ? khi : qhi;
  u16* __restrict__ olo = blockIdx.z ? klo : qlo;

  __shared__ float As[BK][BM];
  __shared__ float Bs[BK][BM];
  const int t = threadIdx.x;
  const int tx = t & 15, ty = t >> 4;
  const int row0 = blockIdx.x * BM;
  const int col0 = blockIdx.y * BM;
  float acc[8][8] = {};
  for (int k0 = 0; k0 < HH; k0 += BK) {
    GEMM_LOAD_TILE(clause, idx[row0 + r], W, col0 + r)
    __syncthreads();
    GEMM_INNER
    __syncthreads();
  }
#pragma unroll
  for (int i = 0; i < 8; ++i) {
    int rl = (i < 4) ? (ty * 4 + i) : (64 + ty * 4 + i - 4);
    size_t rbase = (size_t)(row0 + rl) * HH;
#pragma unroll
    for (int jh = 0; jh < 2; ++jh) {
      int c = col0 + jh * 64 + tx * 4;
      ushort4 hv, lv;
      float v;
      v = acc[i][jh * 4 + 0] + bias[c + 0]; hv.x = f2bf(v); lv.x = f2bf(v - bf2f(hv.x));
      v = acc[i][jh * 4 + 1] + bias[c + 1]; hv.y = f2bf(v); lv.y = f2bf(v - bf2f(hv.y));
      v = acc[i][jh * 4 + 2] + bias[c + 2]; hv.z = f2bf(v); lv.z = f2bf(v - bf2f(hv.z));
      v = acc[i][jh * 4 + 3] + bias[c + 3]; hv.w = f2bf(v); lv.w = f2bf(v - bf2f(hv.w));
      *(ushort4*)(ohi + rbase + c) = hv;
      *(ushort4*)(olo + rbase + c) = lv;
    }
  }
}

// K_t GEMM fused with tanh epilogue -> u partials (per h-block).  (f32 this round)
__global__ __launch_bounds__(256) void ktu_kernel(
    const float* __restrict__ lit, const float* __restrict__ varKw,
    const float* __restrict__ tvec, const float* __restrict__ attnw,
    float* __restrict__ upart) {
  __shared__ float As[BK][BM];
  __shared__ float Bs[BK][BM];
  __shared__ float s_t[BM], s_a[BM];
  const int t = threadIdx.x;
  const int tx = t & 15, ty = t >> 4;
  const int row0 = blockIdx.x * BM;
  const int col0 = blockIdx.y * BM;
  if (t < BM) { s_t[t] = tvec[col0 + t]; s_a[t] = attnw[col0 + t]; }
  float acc[8][8] = {};
  for (int k0 = 0; k0 < HH; k0 += BK) {
    GEMM_LOAD_TILE(lit, row0 + r, varKw, col0 + r)
    __syncthreads();
    GEMM_INNER
    __syncthreads();
  }
  float us[8];
#pragma unroll
  for (int i = 0; i < 8; ++i) {
    float s = 0.f;
#pragma unroll
    for (int j = 0; j < 8; ++j) {
      int cl = (j < 4) ? (tx * 4 + j) : (64 + tx * 4 + j - 4);
      s += tanhf(acc[i][j] + s_t[cl]) * s_a[cl];
    }
    us[i] = s;
  }
#pragma unroll
  for (int m = 1; m < 16; m <<= 1) {
#pragma unroll
    for (int i = 0; i < 8; ++i) us[i] += __shfl_xor(us[i], m, 64);
  }
  if (tx == 0) {
#pragma unroll
    for (int i = 0; i < 8; ++i) {
      int rl = (i < 4) ? (ty * 4 + i) : (64 + ty * 4 + i - 4);
      upart[(size_t)blockIdx.y * NVARS + row0 + rl] = us[i];
    }
  }
}

// ---------------------------------------------------------------------------
// scores = q @ k.T / sqrt(H) via split-bf16 MFMA (hi*hi + hi*lo + lo*hi).
// 128x128 tile, 4 waves (2x2 of 64x64), 16x16x32 MFMA, BK=32, 16 stages.
// LDS rows padded to 80 B (stride 20 words -> max 2-way bank aliasing = free).
__global__ __launch_bounds__(256, 2) void scores_kernel(
    const u16* __restrict__ qhi, const u16* __restrict__ qlo,
    const u16* __restrict__ khi, const u16* __restrict__ klo,
    const unsigned long long* __restrict__ vmask, SPart* __restrict__ parts) {
  __shared__ u16 Ah[128 * 40], Al[128 * 40], Bh[128 * 40], Bl[128 * 40];
  __shared__ unsigned long long mrow[128][2];
  __shared__ float s_rv[4]; __shared__ int s_ri[4]; __shared__ float s_rs[4];
  __shared__ float s_bm; __shared__ int s_ba;

  const int t = threadIdx.x;
  const int lane = t & 63;
  const int wid = t >> 6;
  const int wn = wid & 1, wm = wid >> 1;
  const int n0 = blockIdx.y * 128;   // q rows
  const int m0 = blockIdx.x * 128;   // k rows

  // staging assignment: thread covers rows crow and crow+64, 16B slot cslot
  const int crow = t >> 2, cslot = t & 3;
  uint4 rAh[2], rAl[2], rBh[2], rBl[2];

#define SC_LOAD(s)                                                            \
  {                                                                           \
    const int kb_ = (s) * 32 + cslot * 8;                                     \
    size_t ra0_ = (size_t)(n0 + crow) * HH + kb_;                             \
    size_t ra1_ = (size_t)(n0 + crow + 64) * HH + kb_;                        \
    size_t rb0_ = (size_t)(m0 + crow) * HH + kb_;                             \
    size_t rb1_ = (size_t)(m0 + crow + 64) * HH + kb_;                        \
    rAh[0] = *(const uint4*)(qhi + ra0_); rAh[1] = *(const uint4*)(qhi + ra1_); \
    rAl[0] = *(const uint4*)(qlo + ra0_); rAl[1] = *(const uint4*)(qlo + ra1_); \
    rBh[0] = *(const uint4*)(khi + rb0_); rBh[1] = *(const uint4*)(khi + rb1_); \
    rBl[0] = *(const uint4*)(klo + rb0_); rBl[1] = *(const uint4*)(klo + rb1_); \
  }

#define SC_STORE()                                                            \
  {                                                                           \
    const int l0_ = crow * 40 + cslot * 8;                                    \
    const int l1_ = (crow + 64) * 40 + cslot * 8;                             \
    *(uint4*)&Ah[l0_] = rAh[0]; *(uint4*)&Ah[l1_] = rAh[1];                   \
    *(uint4*)&Al[l0_] = rAl[0]; *(uint4*)&Al[l1_] = rAl[1];                   \
    *(uint4*)&Bh[l0_] = rBh[0]; *(uint4*)&Bh[l1_] = rBh[1];                   \
    *(uint4*)&Bl[l0_] = rBl[0]; *(uint4*)&Bl[l1_] = rBl[1];                   \
  }

  // per-lane MFMA fragment offsets (ushort units): row*40 + (lane>>4)*8
  int aoff[4], boff[4];
#pragma unroll
  for (int f = 0; f < 4; ++f) {
    aoff[f] = (wn * 64 + f * 16 + (lane & 15)) * 40 + (lane >> 4) * 8;
    boff[f] = (wm * 64 + f * 16 + (lane & 15)) * 40 + (lane >> 4) * 8;
  }

  f32x4 acc[4][4] = {};
  SC_LOAD(0)
  for (int s = 0; s < 16; ++s) {
    __syncthreads();           // consumers of previous stage done
    SC_STORE()
    __syncthreads();           // tile ready
    if (s < 15) SC_LOAD(s + 1) // issue next-stage loads early (overlap MFMA)
    bf16x8 ah[4], al[4], bh[4], bl[4];
#pragma unroll
    for (int f = 0; f < 4; ++f) {
      ah[f] = *(const bf16x8*)&Ah[aoff[f]];
      al[f] = *(const bf16x8*)&Al[aoff[f]];
      bh[f] = *(const bf16x8*)&Bh[boff[f]];
      bl[f] = *(const bf16x8*)&Bl[boff[f]];
    }
#pragma unroll
    for (int i = 0; i < 4; ++i)
#pragma unroll
      for (int j = 0; j < 4; ++j) {
        acc[i][j] = __builtin_amdgcn_mfma_f32_16x16x32_bf16(ah[i], bh[j], acc[i][j], 0, 0, 0);
        acc[i][j] = __builtin_amdgcn_mfma_f32_16x16x32_bf16(ah[i], bl[j], acc[i][j], 0, 0, 0);
        acc[i][j] = __builtin_amdgcn_mfma_f32_16x16x32_bf16(al[i], bh[j], acc[i][j], 0, 0, 0);
      }
  }

  // masks
  {
    int r = t >> 1, w = t & 1;
    mrow[r][w] = vmask[(size_t)(n0 + r) * (NMS / 64) + (m0 >> 6) + w];
  }
  __syncthreads();

  // C/D layout (m89-verified): col = lane&15, row = (lane>>4)*4 + reg
  const int rbase = wn * 64 + (lane >> 4) * 4;
  const int cb15 = (lane & 15);

  // phase 1: masked max + argmax (first-occurrence tie-break)
  float mv = NEGV; int mi = 0x7fffffff;
#pragma unroll
  for (int i = 0; i < 4; ++i) {
#pragma unroll
    for (int r = 0; r < 4; ++r) {
      int rl = rbase + i * 16 + r;
      unsigned long long ww = mrow[rl][wm];
      int gb = (n0 + rl) * NMS + m0;
#pragma unroll
      for (int j = 0; j < 4; ++j) {
        int bit = j * 16 + cb15;
        int cl = wm * 64 + bit;
        float sv = acc[i][j][r] * RSQRT_H;
        acc[i][j][r] = sv;
        bool valid = ((ww >> bit) & 1ull) != 0;
        if (valid && (sv > mv || (sv == mv && gb + cl < mi))) { mv = sv; mi = gb + cl; }
      }
    }
  }
  wreduce_maxidx(mv, mi);
  if ((t & 63) == 0) { s_rv[wid] = mv; s_ri[wid] = mi; }
  __syncthreads();
  if (t == 0) {
    float bm = s_rv[0]; int ba = s_ri[0];
    for (int w = 1; w < 4; ++w)
      if (s_rv[w] > bm || (s_rv[w] == bm && s_ri[w] < ba)) { bm = s_rv[w]; ba = s_ri[w]; }
    s_bm = bm; s_ba = ba;
  }
  __syncthreads();
  const float bm = s_bm;

  // phase 2: sum exp(s - blockmax) over valid
  float se = 0.f;
#pragma unroll
  for (int i = 0; i < 4; ++i) {
#pragma unroll
    for (int r = 0; r < 4; ++r) {
      int rl = rbase + i * 16 + r;
      unsigned long long ww = mrow[rl][wm];
#pragma unroll
      for (int j = 0; j < 4; ++j) {
        int bit = j * 16 + cb15;
        bool valid = ((ww >> bit) & 1ull) != 0;
        if (valid) se += __expf(acc[i][j][r] - bm);
      }
    }
  }
  se = wreduce_sum(se);
  if ((t & 63) == 0) s_rs[wid] = se;
  __syncthreads();
  if (t == 0) {
    SPart p;
    p.m = s_bm;
    p.s = s_rs[0] + s_rs[1] + s_rs[2] + s_rs[3];
    p.a = s_ba; p.pad = 0;
    parts[blockIdx.y * gridDim.x + blockIdx.x] = p;
  }
#undef SC_LOAD
#undef SC_STORE
}

// ---------------------------------------------------------------------------
// Final combine.  d_out is FLOAT32 x4: {c_logp, pos_idx[ci], neg_idx[cj], var_idx}.
__global__ __launch_bounds__(256) void final_kernel(
    const float* __restrict__ upart, const SPart* __restrict__ parts,
    const int* __restrict__ pos_idx, const int* __restrict__ neg_idx,
    float* __restrict__ out) {
  __shared__ float s_rv[4]; __shared__ int s_ri[4]; __shared__ float s_rs[4];
  __shared__ float s_umax; __shared__ int s_uarg; __shared__ float s_usum;
  __shared__ float s_gm; __shared__ int s_ga;
  const int t = threadIdx.x;

  float mv = -1.0e38f; int mi = 0x7fffffff;
  for (int i = t; i < NVARS; i += 256) {
    float u = upart[i] + upart[NVARS + i] + upart[2 * NVARS + i] + upart[3 * NVARS + i];
    if (u > mv || (u == mv && i < mi)) { mv = u; mi = i; }
  }
  wreduce_maxidx(mv, mi);
  if ((t & 63) == 0) { s_rv[t >> 6] = mv; s_ri[t >> 6] = mi; }
  __syncthreads();
  if (t == 0) {
    float bm = s_rv[0]; int ba = s_ri[0];
    for (int w = 1; w < 4; ++w)
      if (s_rv[w] > bm || (s_rv[w] == bm && s_ri[w] < ba)) { bm = s_rv[w]; ba = s_ri[w]; }
    s_umax = bm; s_uarg = ba;
  }
  __syncthreads();
  const float umax = s_umax;
  float se = 0.f;
  for (int i = t; i < NVARS; i += 256) {
    float u = upart[i] + upart[NVARS + i] + upart[2 * NVARS + i] + upart[3 * NVARS + i];
    se += __expf(u - umax);
  }
  se = wreduce_sum(se);
  if ((t & 63) == 0) s_rs[t >> 6] = se;
  __syncthreads();
  if (t == 0) s_usum = s_rs[0] + s_rs[1] + s_rs[2] + s_rs[3];
  __syncthreads();

  mv = NEGV; mi = 0x7fffffff;
  for (int i = t; i < 1024; i += 256) {
    SPart p = parts[i];
    if (p.m > mv || (p.m == mv && p.a < mi)) { mv = p.m; mi = p.a; }
  }
  wreduce_maxidx(mv, mi);
  if ((t & 63) == 0) { s_rv[t >> 6] = mv; s_ri[t >> 6] = mi; }
  __syncthreads();
  if (t == 0) {
    float bm = s_rv[0]; int ba = s_ri[0];
    for (int w = 1; w < 4; ++w)
      if (s_rv[w] > bm || (s_rv[w] == bm && s_ri[w] < ba)) { bm = s_rv[w]; ba = s_ri[w]; }
    s_gm = bm; s_ga = ba;
  }
  __syncthreads();
  const float gm = s_gm;
  float ss = 0.f;
  for (int i = t; i < 1024; i += 256) {
    SPart p = parts[i];
    ss += p.s * __expf(p.m - gm);
  }
  ss = wreduce_sum(ss);
  if ((t & 63) == 0) s_rs[t >> 6] = ss;
  __syncthreads();
  if (t == 0) {
    float gsum = s_rs[0] + s_rs[1] + s_rs[2] + s_rs[3];
    float c_logp = -logf(gsum) - logf(s_usum);
    int ga = s_ga;
    if (ga == 0x7fffffff) ga = 0;
    int ci = ga >> 12, cj = ga & 4095;
    out[0] = c_logp;
    out[1] = (float)pos_idx[ci];
    out[2] = (float)neg_idx[cj];
    out[3] = (float)s_uarg;
  }
}

extern "C" void kernel_launch(void* const* d_in, const int* in_sizes, int n_in,
                              void* d_out, int out_size, void* d_ws, size_t ws_size,
                              hipStream_t stream) {
  (void)in_sizes; (void)n_in; (void)out_size; (void)ws_size;
  const float* lit    = (const float*)d_in[0];
  const float* clause = (const float*)d_in[1];
  const int* pos_idx  = (const int*)d_in[2];
  const int* neg_idx  = (const int*)d_in[3];
  const void* keep    = d_in[4];
  const void* taken   = d_in[5];
  const float* varKw  = (const float*)d_in[6];
  const float* varKb  = (const float*)d_in[7];
  const float* varQw  = (const float*)d_in[8];
  const float* varQb  = (const float*)d_in[9];
  const float* attnw  = (const float*)d_in[10];
  // d_in[11] var_attn_b: uniform shift, cancels in log_softmax max/argmax
  const float* WQw    = (const float*)d_in[12];
  const float* WQb    = (const float*)d_in[13];
  const float* WKw    = (const float*)d_in[14];
  const float* WKb    = (const float*)d_in[15];

  char* ws = (char*)d_ws;
  size_t off = 0;
  auto alloc = [&](size_t b) {
    char* p = ws + off;
    off = (off + b + 255) & ~(size_t)255;
    return p;
  };
  int* flag                  = (int*)alloc(4);
  double* qpart              = (double*)alloc((size_t)512 * HH * 8);
  float* tvec                = (float*)alloc(HH * 4);
  float* upart               = (float*)alloc(4 * (size_t)NVARS * 4);
  unsigned long long* vmask  = (unsigned long long*)alloc((size_t)NPOS * (NMS / 64) * 8);
  u16* qhi                   = (u16*)alloc((size_t)NPOS * HH * 2);
  u16* qlo                   = (u16*)alloc((size_t)NPOS * HH * 2);
  u16* khi                   = (u16*)alloc((size_t)NMS * HH * 2);
  u16* klo                   = (u16*)alloc((size_t)NMS * HH * 2);
  SPart* parts               = (SPart*)alloc(1024 * sizeof(SPart));

  detect_kernel<<<1, 64, 0, stream>>>((const unsigned int*)keep, flag);
  pack_kernel<<<16384, 256, 0, stream>>>(keep, taken, flag, vmask);
  qsum_kernel<<<512, 256, 0, stream>>>(clause, qpart);
  prep_kernel<<<1, 512, 0, stream>>>(qpart, varQw, varQb, varKb, tvec);
  proj_kernel<<<dim3(32, 4, 2), 256, 0, stream>>>(clause, pos_idx, neg_idx,
                                                  WQw, WQb, WKw, WKb,
                                                  qhi, qlo, khi, klo);
  ktu_kernel<<<dim3(128, 4), 256, 0, stream>>>(lit, varKw, tvec, attnw, upart);
  scores_kernel<<<dim3(32, 32), 256, 0, stream>>>(qhi, qlo, khi, klo, vmask, parts);
  final_kernel<<<1, 256, 0, stream>>>(upart, parts, pos_idx, neg_idx,
                                      (float*)d_out);
}

// Round 4
// 327.533 us; speedup vs baseline: 1.7160x; 1.5398x over previous
//
#include <hip/hip_runtime.h>
#include <hip/hip_bf16.h>
#include <math.h>

#define HH 512
#define NVARS 16384
#define NPOS 4096
#define NMS 4096
#define NEGV -1.0e30f
#define RSQRT_H 0.04419417382415922f   // 1/sqrt(512)

#define BM 128
#define BK 16

typedef unsigned short u16;
typedef __attribute__((ext_vector_type(8))) short bf16x8;
typedef __attribute__((ext_vector_type(4))) float f32x4;

struct SPart { float m; float s; int a; int pad; };

__device__ inline u16 f2bf(float f) {
  unsigned u = __float_as_uint(f);
  unsigned r = (u + 0x7fffu + ((u >> 16) & 1u)) >> 16;
  return (u16)r;
}
__device__ inline float bf2f(u16 h) { return __uint_as_float(((unsigned)h) << 16); }

__device__ inline void wreduce_maxidx(float& v, int& idx) {
#pragma unroll
  for (int m = 1; m < 64; m <<= 1) {
    float ov = __shfl_xor(v, m, 64);
    int oi = __shfl_xor(idx, m, 64);
    if (ov > v || (ov == v && oi < idx)) { v = ov; idx = oi; }
  }
}

__device__ inline float wreduce_sum(float v) {
#pragma unroll
  for (int m = 1; m < 64; m <<= 1) v += __shfl_xor(v, m, 64);
  return v;
}

// ---------------------------------------------------------------------------
__global__ void detect_kernel(const unsigned int* __restrict__ keep, int* __restrict__ flag) {
  if (threadIdx.x == 0 && blockIdx.x == 0) {
    int ok = 1;
    for (int i = 0; i < 64; ++i) if (keep[i] > 1u) ok = 0;
    *flag = ok;   // 1: int32 masks, 0: byte masks
  }
}

__global__ __launch_bounds__(256) void pack_kernel(
    const void* __restrict__ keep, const void* __restrict__ taken,
    const int* __restrict__ flag, unsigned long long* __restrict__ vmask) {
  const int f = *flag;
  const int t = threadIdx.x;
#pragma unroll
  for (int it = 0; it < 4; ++it) {
    size_t e = (size_t)blockIdx.x * 1024 + (size_t)it * 256 + t;
    int kv, tv;
    if (f) {
      kv = ((const int*)keep)[e];
      tv = ((const int*)taken)[e];
    } else {
      kv = ((const unsigned char*)keep)[e];
      tv = ((const unsigned char*)taken)[e];
    }
    unsigned long long m = __ballot(kv != 0 && tv == 0);
    if ((t & 63) == 0) vmask[e >> 6] = m;
  }
}

// ---------------------------------------------------------------------------
__global__ __launch_bounds__(256) void qsum_kernel(
    const float* __restrict__ clause, double* __restrict__ qpart) {
  const int b = blockIdx.x, t = threadIdx.x;
  const float* base = clause + (size_t)b * 128 * HH;
  double a0 = 0.0, a1 = 0.0;
#pragma unroll 4
  for (int r = 0; r < 128; ++r) {
    a0 += (double)base[(size_t)r * HH + t];
    a1 += (double)base[(size_t)r * HH + t + 256];
  }
  qpart[b * HH + t] = a0;
  qpart[b * HH + t + 256] = a1;
}

// reduce 512 partial Q vectors -> Qd[512] (f64)
__global__ __launch_bounds__(256) void qred_kernel(
    const double* __restrict__ qpart, double* __restrict__ Qd) {
  __shared__ double red[256];
  const int t = threadIdx.x;
  const int h = blockIdx.x * 16 + (t & 15);
  const int chunk = t >> 4;
  double s = 0.0;
  for (int j = 0; j < 32; ++j) s += qpart[(size_t)(chunk * 32 + j) * HH + h];
  red[t] = s;
  __syncthreads();
  for (int off = 8; off > 0; off >>= 1) {
    if (chunk < off) red[t] += red[t + off * 16];
    __syncthreads();
  }
  if (t < 16) Qd[blockIdx.x * 16 + t] = red[t];
}

// tvec[h] = (Q @ var_Q_w.T)[h] + var_Q_b[h] + var_K_b[h]
__global__ __launch_bounds__(256) void prepmv_kernel(
    const double* __restrict__ Qd, const float* __restrict__ varQw,
    const float* __restrict__ varQb, const float* __restrict__ varKb,
    float* __restrict__ tvec) {
  __shared__ double red[256];
  const int t = threadIdx.x;
  const int h = blockIdx.x * 16 + (t & 15);
  const int chunk = t >> 4;
  const float* wrow = varQw + (size_t)h * HH + chunk * 32;
  const double* qd = Qd + chunk * 32;
  double s = 0.0;
  for (int j = 0; j < 32; ++j) s += qd[j] * (double)wrow[j];
  red[t] = s;
  __syncthreads();
  for (int off = 8; off > 0; off >>= 1) {
    if (chunk < off) red[t] += red[t + off * 16];
    __syncthreads();
  }
  if (t < 16) {
    int hh = blockIdx.x * 16 + t;
    tvec[hh] = (float)(red[t] + (double)varQb[hh] + (double)varKb[hh]);
  }
}

// ---------------------------------------------------------------------------
// convert a row-major f32 matrix [nrow x 512] into fragment-major bf16 hi/lo.
// frag f covers rows (f>>4)*16..+16, cols (f&15)*32..+32; within a frag,
// lane l holds row (l&15), k-chunk (l>>4)*8 (8 consecutive u16 = 16 B).
__global__ __launch_bounds__(256) void tofrag_kernel(
    const float* __restrict__ src, u16* __restrict__ hi, u16* __restrict__ lo) {
  const int frag = blockIdx.x * 4 + (threadIdx.x >> 6);
  const int lane = threadIdx.x & 63;
  const int R = frag >> 4, K = frag & 15;
  const float* p = src + (size_t)(R * 16 + (lane & 15)) * HH + K * 32 + (lane >> 4) * 8;
  float v[8];
  *(float4*)&v[0] = *(const float4*)p;
  *(float4*)&v[4] = *(const float4*)(p + 4);
  u16 h[8], l[8];
#pragma unroll
  for (int e = 0; e < 8; ++e) { h[e] = f2bf(v[e]); l[e] = f2bf(v[e] - bf2f(h[e])); }
  size_t base = (size_t)frag * 512 + (size_t)lane * 8;
  *(ushort4*)(hi + base) = *(ushort4*)&h[0];
  *(ushort4*)(hi + base + 4) = *(ushort4*)&h[4];
  *(ushort4*)(lo + base) = *(ushort4*)&l[0];
  *(ushort4*)(lo + base + 4) = *(ushort4*)&l[4];
}

// ---------------------------------------------------------------------------
// f32 tiled NT-GEMM pieces (proj only)

#define GEMM_LOAD_TILE(APTR, AROWEXPR, BPTR, BROWEXPR)                               \
  _Pragma("unroll")                                                                  \
  for (int qq = 0; qq < 2; ++qq) {                                                   \
    int fidx = t * 2 + qq;                                                           \
    int r = fidx >> 2;                                                               \
    int jc = (fidx & 3) * 4;                                                         \
    int arow_ = (AROWEXPR);                                                          \
    float4 va = *(const float4*)((APTR) + (size_t)arow_ * HH + k0 + jc);             \
    As[jc + 0][r] = va.x; As[jc + 1][r] = va.y;                                      \
    As[jc + 2][r] = va.z; As[jc + 3][r] = va.w;                                      \
    int brow_ = (BROWEXPR);                                                          \
    float4 vb = *(const float4*)((BPTR) + (size_t)brow_ * HH + k0 + jc);             \
    Bs[jc + 0][r] = vb.x; Bs[jc + 1][r] = vb.y;                                      \
    Bs[jc + 2][r] = vb.z; Bs[jc + 3][r] = vb.w;                                      \
  }

#define GEMM_INNER                                                                   \
  _Pragma("unroll")                                                                  \
  for (int k = 0; k < BK; ++k) {                                                     \
    float av[8], bv[8];                                                              \
    *(float4*)&av[0] = *(const float4*)&As[k][ty * 4];                               \
    *(float4*)&av[4] = *(const float4*)&As[k][64 + ty * 4];                          \
    *(float4*)&bv[0] = *(const float4*)&Bs[k][tx * 4];                               \
    *(float4*)&bv[4] = *(const float4*)&Bs[k][64 + tx * 4];                          \
    _Pragma("unroll")                                                                \
    for (int i = 0; i < 8; ++i)                                                      \
      _Pragma("unroll")                                                              \
      for (int j = 0; j < 8; ++j)                                                    \
        acc[i][j] += av[i] * bv[j];                                                  \
  }

// q/k projection with row gather; epilogue writes fragment-major bf16 hi/lo.
__global__ __launch_bounds__(256) void proj_kernel(
    const float* __restrict__ clause,
    const int* __restrict__ pos_idx, const int* __restrict__ neg_idx,
    const float* __restrict__ WQ, const float* __restrict__ bQ,
    const float* __restrict__ WK, const float* __restrict__ bK,
    u16* __restrict__ qhi, u16* __restrict__ qlo,
    u16* __restrict__ khi, u16* __restrict__ klo) {
  const int* __restrict__ idx = blockIdx.z ? neg_idx : pos_idx;
  const float* __restrict__ W = blockIdx.z ? WK : WQ;
  const float* __restrict__ bias = blockIdx.z ? bK : bQ;
  u16* __restrict__ ohi = blockIdx.z ? khi : qhi;
  u16* __restrict__ olo = blockIdx.z ? klo : qlo;

  __shared__ float As[BK][BM];
  __shared__ float Bs[BK][BM];
  const int t = threadIdx.x;
  const int tx = t & 15, ty = t >> 4;
  const int row0 = blockIdx.x * BM;
  const int col0 = blockIdx.y * BM;
  float acc[8][8] = {};
  for (int k0 = 0; k0 < HH; k0 += BK) {
    GEMM_LOAD_TILE(clause, idx[row0 + r], W, col0 + r)
    __syncthreads();
    GEMM_INNER
    __syncthreads();
  }
#pragma unroll
  for (int i = 0; i < 8; ++i) {
    int rl = (i < 4) ? (ty * 4 + i) : (64 + ty * 4 + i - 4);
    int grow = row0 + rl;
    int Rf = grow >> 4, rl16 = grow & 15;
#pragma unroll
    for (int jh = 0; jh < 2; ++jh) {
      int c = col0 + jh * 64 + tx * 4;
      int Kf = c >> 5;
      int lane16 = rl16 + ((c & 31) >> 3) * 16;
      int sub = c & 7;
      size_t flat = ((size_t)(Rf * 16 + Kf)) * 512 + (size_t)lane16 * 8 + sub;
      ushort4 hv, lv;
      float v;
      v = acc[i][jh * 4 + 0] + bias[c + 0]; hv.x = f2bf(v); lv.x = f2bf(v - bf2f(hv.x));
      v = acc[i][jh * 4 + 1] + bias[c + 1]; hv.y = f2bf(v); lv.y = f2bf(v - bf2f(hv.y));
      v = acc[i][jh * 4 + 2] + bias[c + 2]; hv.z = f2bf(v); lv.z = f2bf(v - bf2f(hv.z));
      v = acc[i][jh * 4 + 3] + bias[c + 3]; hv.w = f2bf(v); lv.w = f2bf(v - bf2f(hv.w));
      *(ushort4*)(ohi + flat) = hv;
      *(ushort4*)(olo + flat) = lv;
    }
  }
}

// ---------------------------------------------------------------------------
// shared MFMA macro: 3-pass split accumulate (hh, hl, lh)
#define MFMAS(AH, AL, BH, BL)                                                        \
  do {                                                                               \
    _Pragma("unroll") for (int i_ = 0; i_ < 4; ++i_)                                 \
    _Pragma("unroll") for (int j_ = 0; j_ < 4; ++j_) {                               \
      acc[i_][j_] = __builtin_amdgcn_mfma_f32_16x16x32_bf16(AH[i_], BH[j_], acc[i_][j_], 0, 0, 0); \
      acc[i_][j_] = __builtin_amdgcn_mfma_f32_16x16x32_bf16(AH[i_], BL[j_], acc[i_][j_], 0, 0, 0); \
      acc[i_][j_] = __builtin_amdgcn_mfma_f32_16x16x32_bf16(AL[i_], BH[j_], acc[i_][j_], 0, 0, 0); \
    }                                                                                \
  } while (0)

// ---------------------------------------------------------------------------
// K_t GEMM (lit @ varKw.T) via MFMA with on-the-fly A split; tanh epilogue.
__global__ __launch_bounds__(256, 2) void ktu_kernel(
    const float* __restrict__ lit,
    const u16* __restrict__ wkhi, const u16* __restrict__ wklo,
    const float* __restrict__ tvec, const float* __restrict__ attnw,
    float* __restrict__ upart) {
  const int t = threadIdx.x, lane = t & 63, wid = t >> 6;
  const int wn = wid & 1, wm = wid >> 1;
  const int row0 = blockIdx.x * 128;
  const int arow0 = row0 + wn * 64 + (lane & 15);
  const int kcol = (lane >> 4) * 8;
  const size_t bbase = (size_t)(blockIdx.y * 8 + wm * 4) * 8192 + (size_t)lane * 8;

#define KLOADA(s, RAW)                                                               \
  do {                                                                               \
    _Pragma("unroll") for (int f_ = 0; f_ < 4; ++f_) {                               \
      const float* p_ = lit + (size_t)(arow0 + f_ * 16) * HH + (s) * 32 + kcol;      \
      *(float4*)&RAW[f_][0] = *(const float4*)p_;                                    \
      *(float4*)&RAW[f_][4] = *(const float4*)(p_ + 4);                              \
    }                                                                                \
  } while (0)

#define KLOADB(s, BH, BL)                                                            \
  do {                                                                               \
    _Pragma("unroll") for (int f_ = 0; f_ < 4; ++f_) {                               \
      size_t o_ = bbase + (size_t)f_ * 8192 + (size_t)(s) * 512;                     \
      BH[f_] = *(const bf16x8*)(wkhi + o_);                                          \
      BL[f_] = *(const bf16x8*)(wklo + o_);                                          \
    }                                                                                \
  } while (0)

#define KCONV(RAW, AH, AL)                                                           \
  do {                                                                               \
    _Pragma("unroll") for (int f_ = 0; f_ < 4; ++f_)                                 \
    _Pragma("unroll") for (int e_ = 0; e_ < 8; ++e_) {                               \
      float v_ = RAW[f_][e_];                                                        \
      u16 h_ = f2bf(v_);                                                             \
      AH[f_][e_] = (short)h_;                                                        \
      AL[f_][e_] = (short)f2bf(v_ - bf2f(h_));                                       \
    }                                                                                \
  } while (0)

  f32x4 acc[4][4] = {};
  float rA0[4][8], rA1[4][8];
  bf16x8 fAH[4], fAL[4], bH0[4], bL0[4], bH1[4], bL1[4];
  KLOADA(0, rA0); KLOADB(0, bH0, bL0);
#pragma unroll
  for (int s = 0; s < 16; s += 2) {
    KLOADA(s + 1, rA1); KLOADB(s + 1, bH1, bL1);
    KCONV(rA0, fAH, fAL);
    MFMAS(fAH, fAL, bH0, bL0);
    if (s + 2 < 16) { KLOADA(s + 2, rA0); KLOADB(s + 2, bH0, bL0); }
    KCONV(rA1, fAH, fAL);
    MFMAS(fAH, fAL, bH1, bL1);
  }

  // epilogue: u partial = sum_c tanh(K_t + tvec[c]) * attnw[c]
  const int cbase = blockIdx.y * 128 + wm * 64;
  float tv[4], aw[4];
#pragma unroll
  for (int j = 0; j < 4; ++j) {
    int c = cbase + j * 16 + (lane & 15);
    tv[j] = tvec[c]; aw[j] = attnw[c];
  }
  float us[4][4];
#pragma unroll
  for (int i = 0; i < 4; ++i)
#pragma unroll
    for (int r = 0; r < 4; ++r) {
      float s = 0.f;
#pragma unroll
      for (int j = 0; j < 4; ++j) {
        float x = acc[i][j][r] + tv[j];
        float th = 1.0f - 2.0f / (__expf(2.0f * x) + 1.0f);   // safe tanh
        s += th * aw[j];
      }
      us[i][r] = s;
    }
#pragma unroll
  for (int m = 1; m < 16; m <<= 1)
#pragma unroll
    for (int i = 0; i < 4; ++i)
#pragma unroll
      for (int r = 0; r < 4; ++r) us[i][r] += __shfl_xor(us[i][r], m, 64);
  if ((lane & 15) == 0) {
#pragma unroll
    for (int i = 0; i < 4; ++i)
#pragma unroll
      for (int r = 0; r < 4; ++r) {
        int row = row0 + wn * 64 + i * 16 + (lane >> 4) * 4 + r;
        upart[(size_t)(blockIdx.y * 2 + wm) * NVARS + row] = us[i][r];
      }
  }
#undef KLOADA
#undef KLOADB
#undef KCONV
}

// ---------------------------------------------------------------------------
// scores = q @ k.T / sqrt(H) via split-bf16 MFMA, fragment-major global reads,
// NO LDS staging (panels are L2-resident); 2-deep register pipeline.
__global__ __launch_bounds__(256, 2) void scores_kernel(
    const u16* __restrict__ qhi, const u16* __restrict__ qlo,
    const u16* __restrict__ khi, const u16* __restrict__ klo,
    const unsigned long long* __restrict__ vmask, SPart* __restrict__ parts) {
  __shared__ unsigned long long mrow[128][2];
  __shared__ float s_rv[4]; __shared__ int s_ri[4]; __shared__ float s_rs[4];
  __shared__ float s_bm; __shared__ int s_ba;

  const int t = threadIdx.x;
  const int lane = t & 63;
  const int wid = t >> 6;
  const int wn = wid & 1, wm = wid >> 1;
  const int n0 = blockIdx.y * 128;   // q rows
  const int m0 = blockIdx.x * 128;   // k rows
  const size_t abase = (size_t)((n0 >> 4) + wn * 4) * 8192 + (size_t)lane * 8;
  const size_t bbase = (size_t)((m0 >> 4) + wm * 4) * 8192 + (size_t)lane * 8;

#define LOADF(s, AH, AL, BH, BL)                                                     \
  do {                                                                               \
    _Pragma("unroll") for (int f_ = 0; f_ < 4; ++f_) {                               \
      size_t oa_ = abase + (size_t)f_ * 8192 + (size_t)(s) * 512;                    \
      size_t ob_ = bbase + (size_t)f_ * 8192 + (size_t)(s) * 512;                    \
      AH[f_] = *(const bf16x8*)(qhi + oa_);                                          \
      AL[f_] = *(const bf16x8*)(qlo + oa_);                                          \
      BH[f_] = *(const bf16x8*)(khi + ob_);                                          \
      BL[f_] = *(const bf16x8*)(klo + ob_);                                          \
    }                                                                                \
  } while (0)

  f32x4 acc[4][4] = {};
  bf16x8 aH0[4], aL0[4], bH0[4], bL0[4];
  bf16x8 aH1[4], aL1[4], bH1[4], bL1[4];
  LOADF(0, aH0, aL0, bH0, bL0);
#pragma unroll
  for (int s = 0; s < 16; s += 2) {
    LOADF(s + 1, aH1, aL1, bH1, bL1);
    MFMAS(aH0, aL0, bH0, bL0);
    if (s + 2 < 16) LOADF(s + 2, aH0, aL0, bH0, bL0);
    MFMAS(aH1, aL1, bH1, bL1);
  }

  // masks
  {
    int r = t >> 1, w = t & 1;
    mrow[r][w] = vmask[(size_t)(n0 + r) * (NMS / 64) + (m0 >> 6) + w];
  }
  __syncthreads();

  // C/D layout: col = lane&15, row = (lane>>4)*4 + reg
  const int rbase = wn * 64 + (lane >> 4) * 4;
  const int cb15 = (lane & 15);

  float mv = NEGV; int mi = 0x7fffffff;
#pragma unroll
  for (int i = 0; i < 4; ++i) {
#pragma unroll
    for (int r = 0; r < 4; ++r) {
      int rl = rbase + i * 16 + r;
      unsigned long long ww = mrow[rl][wm];
      int gb = (n0 + rl) * NMS + m0;
#pragma unroll
      for (int j = 0; j < 4; ++j) {
        int bit = j * 16 + cb15;
        int cl = wm * 64 + bit;
        float sv = acc[i][j][r] * RSQRT_H;
        acc[i][j][r] = sv;
        bool valid = ((ww >> bit) & 1ull) != 0;
        if (valid && (sv > mv || (sv == mv && gb + cl < mi))) { mv = sv; mi = gb + cl; }
      }
    }
  }
  wreduce_maxidx(mv, mi);
  if ((t & 63) == 0) { s_rv[wid] = mv; s_ri[wid] = mi; }
  __syncthreads();
  if (t == 0) {
    float bm = s_rv[0]; int ba = s_ri[0];
    for (int w = 1; w < 4; ++w)
      if (s_rv[w] > bm || (s_rv[w] == bm && s_ri[w] < ba)) { bm = s_rv[w]; ba = s_ri[w]; }
    s_bm = bm; s_ba = ba;
  }
  __syncthreads();
  const float bm = s_bm;

  float se = 0.f;
#pragma unroll
  for (int i = 0; i < 4; ++i) {
#pragma unroll
    for (int r = 0; r < 4; ++r) {
      int rl = rbase + i * 16 + r;
      unsigned long long ww = mrow[rl][wm];
#pragma unroll
      for (int j = 0; j < 4; ++j) {
        int bit = j * 16 + cb15;
        bool valid = ((ww >> bit) & 1ull) != 0;
        if (valid) se += __expf(acc[i][j][r] - bm);
      }
    }
  }
  se = wreduce_sum(se);
  if ((t & 63) == 0) s_rs[wid] = se;
  __syncthreads();
  if (t == 0) {
    SPart p;
    p.m = s_bm;
    p.s = s_rs[0] + s_rs[1] + s_rs[2] + s_rs[3];
    p.a = s_ba; p.pad = 0;
    parts[blockIdx.y * gridDim.x + blockIdx.x] = p;
  }
#undef LOADF
}

// ---------------------------------------------------------------------------
// Final combine.  d_out is FLOAT32 x4: {c_logp, pos_idx[ci], neg_idx[cj], var_idx}.
__global__ __launch_bounds__(256) void final_kernel(
    const float* __restrict__ upart, const SPart* __restrict__ parts,
    const int* __restrict__ pos_idx, const int* __restrict__ neg_idx,
    float* __restrict__ out) {
  __shared__ float s_rv[4]; __shared__ int s_ri[4]; __shared__ float s_rs[4];
  __shared__ float s_umax; __shared__ int s_uarg; __shared__ float s_usum;
  __shared__ float s_gm; __shared__ int s_ga;
  const int t = threadIdx.x;

  float mv = -1.0e38f; int mi = 0x7fffffff;
  for (int i = t; i < NVARS; i += 256) {
    float u = 0.f;
#pragma unroll
    for (int p = 0; p < 8; ++p) u += upart[(size_t)p * NVARS + i];
    if (u > mv || (u == mv && i < mi)) { mv = u; mi = i; }
  }
  wreduce_maxidx(mv, mi);
  if ((t & 63) == 0) { s_rv[t >> 6] = mv; s_ri[t >> 6] = mi; }
  __syncthreads();
  if (t == 0) {
    float bm = s_rv[0]; int ba = s_ri[0];
    for (int w = 1; w < 4; ++w)
      if (s_rv[w] > bm || (s_rv[w] == bm && s_ri[w] < ba)) { bm = s_rv[w]; ba = s_ri[w]; }
    s_umax = bm; s_uarg = ba;
  }
  __syncthreads();
  const float umax = s_umax;
  float se = 0.f;
  for (int i = t; i < NVARS; i += 256) {
    float u = 0.f;
#pragma unroll
    for (int p = 0; p < 8; ++p) u += upart[(size_t)p * NVARS + i];
    se += __expf(u - umax);
  }
  se = wreduce_sum(se);
  if ((t & 63) == 0) s_rs[t >> 6] = se;
  __syncthreads();
  if (t == 0) s_usum = s_rs[0] + s_rs[1] + s_rs[2] + s_rs[3];
  __syncthreads();

  mv = NEGV; mi = 0x7fffffff;
  for (int i = t; i < 1024; i += 256) {
    SPart p = parts[i];
    if (p.m > mv || (p.m == mv && p.a < mi)) { mv = p.m; mi = p.a; }
  }
  wreduce_maxidx(mv, mi);
  if ((t & 63) == 0) { s_rv[t >> 6] = mv; s_ri[t >> 6] = mi; }
  __syncthreads();
  if (t == 0) {
    float bm = s_rv[0]; int ba = s_ri[0];
    for (int w = 1; w < 4; ++w)
      if (s_rv[w] > bm || (s_rv[w] == bm && s_ri[w] < ba)) { bm = s_rv[w]; ba = s_ri[w]; }
    s_gm = bm; s_ga = ba;
  }
  __syncthreads();
  const float gm = s_gm;
  float ss = 0.f;
  for (int i = t; i < 1024; i += 256) {
    SPart p = parts[i];
    ss += p.s * __expf(p.m - gm);
  }
  ss = wreduce_sum(ss);
  if ((t & 63) == 0) s_rs[t >> 6] = ss;
  __syncthreads();
  if (t == 0) {
    float gsum = s_rs[0] + s_rs[1] + s_rs[2] + s_rs[3];
    float c_logp = -logf(gsum) - logf(s_usum);
    int ga = s_ga;
    if (ga == 0x7fffffff) ga = 0;
    int ci = ga >> 12, cj = ga & 4095;
    out[0] = c_logp;
    out[1] = (float)pos_idx[ci];
    out[2] = (float)neg_idx[cj];
    out[3] = (float)s_uarg;
  }
}

extern "C" void kernel_launch(void* const* d_in, const int* in_sizes, int n_in,
                              void* d_out, int out_size, void* d_ws, size_t ws_size,
                              hipStream_t stream) {
  (void)in_sizes; (void)n_in; (void)out_size; (void)ws_size;
  const float* lit    = (const float*)d_in[0];
  const float* clause = (const float*)d_in[1];
  const int* pos_idx  = (const int*)d_in[2];
  const int* neg_idx  = (const int*)d_in[3];
  const void* keep    = d_in[4];
  const void* taken   = d_in[5];
  const float* varKw  = (const float*)d_in[6];
  const float* varKb  = (const float*)d_in[7];
  const float* varQw  = (const float*)d_in[8];
  const float* varQb  = (const float*)d_in[9];
  const float* attnw  = (const float*)d_in[10];
  // d_in[11] var_attn_b: uniform shift, cancels in log_softmax max/argmax
  const float* WQw    = (const float*)d_in[12];
  const float* WQb    = (const float*)d_in[13];
  const float* WKw    = (const float*)d_in[14];
  const float* WKb    = (const float*)d_in[15];

  char* ws = (char*)d_ws;
  size_t off = 0;
  auto alloc = [&](size_t b) {
    char* p = ws + off;
    off = (off + b + 255) & ~(size_t)255;
    return p;
  };
  int* flag                  = (int*)alloc(4);
  double* qpart              = (double*)alloc((size_t)512 * HH * 8);
  double* Qd                 = (double*)alloc(HH * 8);
  float* tvec                = (float*)alloc(HH * 4);
  float* upart               = (float*)alloc(8 * (size_t)NVARS * 4);
  unsigned long long* vmask  = (unsigned long long*)alloc((size_t)NPOS * (NMS / 64) * 8);
  u16* qhi                   = (u16*)alloc((size_t)NPOS * HH * 2);
  u16* qlo                   = (u16*)alloc((size_t)NPOS * HH * 2);
  u16* khi                   = (u16*)alloc((size_t)NMS * HH * 2);
  u16* klo                   = (u16*)alloc((size_t)NMS * HH * 2);
  u16* wkhi                  = (u16*)alloc((size_t)HH * HH * 2);
  u16* wklo                  = (u16*)alloc((size_t)HH * HH * 2);
  SPart* parts               = (SPart*)alloc(1024 * sizeof(SPart));

  detect_kernel<<<1, 64, 0, stream>>>((const unsigned int*)keep, flag);
  pack_kernel<<<16384, 256, 0, stream>>>(keep, taken, flag, vmask);
  qsum_kernel<<<512, 256, 0, stream>>>(clause, qpart);
  qred_kernel<<<32, 256, 0, stream>>>(qpart, Qd);
  prepmv_kernel<<<32, 256, 0, stream>>>(Qd, varQw, varQb, varKb, tvec);
  tofrag_kernel<<<128, 256, 0, stream>>>(varKw, wkhi, wklo);
  proj_kernel<<<dim3(32, 4, 2), 256, 0, stream>>>(clause, pos_idx, neg_idx,
                                                  WQw, WQb, WKw, WKb,
                                                  qhi, qlo, khi, klo);
  ktu_kernel<<<dim3(128, 4), 256, 0, stream>>>(lit, wkhi, wklo, tvec, attnw, upart);
  scores_kernel<<<dim3(32, 32), 256, 0, stream>>>(qhi, qlo, khi, klo, vmask, parts);
  final_kernel<<<1, 256, 0, stream>>>(upart, parts, pos_idx, neg_idx,
                                      (float*)d_out);
}

// Round 5
// 320.737 us; speedup vs baseline: 1.7524x; 1.0212x over previous
//
#include <hip/hip_runtime.h>
#include <hip/hip_bf16.h>
#include <math.h>

#define HH 512
#define NVARS 16384
#define NPOS 4096
#define NMS 4096
#define NEGV -1.0e30f
#define RSQRT_H 0.04419417382415922f   // 1/sqrt(512)

#define BM 128
#define BK 16

typedef unsigned short u16;
typedef __attribute__((ext_vector_type(8))) short bf16x8;
typedef __attribute__((ext_vector_type(4))) float f32x4;

struct SPart { float m; float s; int a; int pad; };

__device__ inline u16 f2bf(float f) {
  unsigned u = __float_as_uint(f);
  unsigned r = (u + 0x7fffu + ((u >> 16) & 1u)) >> 16;
  return (u16)r;
}
__device__ inline float bf2f(u16 h) { return __uint_as_float(((unsigned)h) << 16); }

__device__ inline void wreduce_maxidx(float& v, int& idx) {
#pragma unroll
  for (int m = 1; m < 64; m <<= 1) {
    float ov = __shfl_xor(v, m, 64);
    int oi = __shfl_xor(idx, m, 64);
    if (ov > v || (ov == v && oi < idx)) { v = ov; idx = oi; }
  }
}

__device__ inline float wreduce_sum(float v) {
#pragma unroll
  for (int m = 1; m < 64; m <<= 1) v += __shfl_xor(v, m, 64);
  return v;
}

// ---------------------------------------------------------------------------
__global__ void detect_kernel(const unsigned int* __restrict__ keep, int* __restrict__ flag) {
  if (threadIdx.x == 0 && blockIdx.x == 0) {
    int ok = 1;
    for (int i = 0; i < 64; ++i) if (keep[i] > 1u) ok = 0;
    *flag = ok;   // 1: int32 masks, 0: byte masks
  }
}

__global__ __launch_bounds__(256) void pack_kernel(
    const void* __restrict__ keep, const void* __restrict__ taken,
    const int* __restrict__ flag, unsigned long long* __restrict__ vmask) {
  const int f = *flag;
  const int t = threadIdx.x;
#pragma unroll
  for (int it = 0; it < 4; ++it) {
    size_t e = (size_t)blockIdx.x * 1024 + (size_t)it * 256 + t;
    int kv, tv;
    if (f) {
      kv = ((const int*)keep)[e];
      tv = ((const int*)taken)[e];
    } else {
      kv = ((const unsigned char*)keep)[e];
      tv = ((const unsigned char*)taken)[e];
    }
    unsigned long long m = __ballot(kv != 0 && tv == 0);
    if ((t & 63) == 0) vmask[e >> 6] = m;
  }
}

// ---------------------------------------------------------------------------
// Q partial sums; float4 loads (16B/lane), 2 row-halves x 128 col-groups.
__global__ __launch_bounds__(256) void qsum_kernel(
    const float* __restrict__ clause, double* __restrict__ qpart) {
  const int b = blockIdx.x, t = threadIdx.x;
  const int fg = t & 127;   // float4 column group (covers cols 4fg..4fg+3)
  const int rh = t >> 7;    // row half
  const float* base = clause + (size_t)(b * 128 + rh * 64) * HH + fg * 4;
  double a0 = 0.0, a1 = 0.0, a2 = 0.0, a3 = 0.0;
#pragma unroll 4
  for (int r = 0; r < 64; ++r) {
    float4 v = *(const float4*)(base + (size_t)r * HH);
    a0 += (double)v.x; a1 += (double)v.y; a2 += (double)v.z; a3 += (double)v.w;
  }
  double* o = qpart + (size_t)(b * 2 + rh) * HH + fg * 4;
  o[0] = a0; o[1] = a1; o[2] = a2; o[3] = a3;
}

// reduce 1024 partial Q vectors -> Qd[512] (f64)
__global__ __launch_bounds__(256) void qred_kernel(
    const double* __restrict__ qpart, double* __restrict__ Qd) {
  __shared__ double red[256];
  const int t = threadIdx.x;
  const int h = blockIdx.x * 16 + (t & 15);
  const int chunk = t >> 4;
  double s = 0.0;
  for (int j = 0; j < 64; ++j) s += qpart[(size_t)(chunk * 64 + j) * HH + h];
  red[t] = s;
  __syncthreads();
  for (int off = 8; off > 0; off >>= 1) {
    if (chunk < off) red[t] += red[t + off * 16];
    __syncthreads();
  }
  if (t < 16) Qd[blockIdx.x * 16 + t] = red[t];
}

// tvec[h] = (Q @ var_Q_w.T)[h] + var_Q_b[h] + var_K_b[h]
__global__ __launch_bounds__(256) void prepmv_kernel(
    const double* __restrict__ Qd, const float* __restrict__ varQw,
    const float* __restrict__ varQb, const float* __restrict__ varKb,
    float* __restrict__ tvec) {
  __shared__ double red[256];
  const int t = threadIdx.x;
  const int h = blockIdx.x * 16 + (t & 15);
  const int chunk = t >> 4;
  const float* wrow = varQw + (size_t)h * HH + chunk * 32;
  const double* qd = Qd + chunk * 32;
  double s = 0.0;
  for (int j = 0; j < 32; ++j) s += qd[j] * (double)wrow[j];
  red[t] = s;
  __syncthreads();
  for (int off = 8; off > 0; off >>= 1) {
    if (chunk < off) red[t] += red[t + off * 16];
    __syncthreads();
  }
  if (t < 16) {
    int hh = blockIdx.x * 16 + t;
    tvec[hh] = (float)(red[t] + (double)varQb[hh] + (double)varKb[hh]);
  }
}

// ---------------------------------------------------------------------------
// convert a row-major f32 matrix [nrow x 512] into fragment-major bf16 hi/lo.
// frag f: rows (f>>4)*16..+16, cols (f&15)*32..+32; lane l holds row (l&15),
// k-chunk (l>>4)*8. flat addr = f*512 + lane*8.
__global__ __launch_bounds__(256) void tofrag_kernel(
    const float* __restrict__ src, u16* __restrict__ hi, u16* __restrict__ lo) {
  const int frag = blockIdx.x * 4 + (threadIdx.x >> 6);
  const int lane = threadIdx.x & 63;
  const int R = frag >> 4, K = frag & 15;
  const float* p = src + (size_t)(R * 16 + (lane & 15)) * HH + K * 32 + (lane >> 4) * 8;
  float v[8];
  *(float4*)&v[0] = *(const float4*)p;
  *(float4*)&v[4] = *(const float4*)(p + 4);
  u16 h[8], l[8];
#pragma unroll
  for (int e = 0; e < 8; ++e) { h[e] = f2bf(v[e]); l[e] = f2bf(v[e] - bf2f(h[e])); }
  size_t base = (size_t)frag * 512 + (size_t)lane * 8;
  *(ushort4*)(hi + base) = *(ushort4*)&h[0];
  *(ushort4*)(hi + base + 4) = *(ushort4*)&h[4];
  *(ushort4*)(lo + base) = *(ushort4*)&l[0];
  *(ushort4*)(lo + base + 4) = *(ushort4*)&l[4];
}

// ---------------------------------------------------------------------------
// f32 tiled NT-GEMM pieces (proj only)

#define GEMM_LOAD_TILE(APTR, AROWEXPR, BPTR, BROWEXPR)                               \
  _Pragma("unroll")                                                                  \
  for (int qq = 0; qq < 2; ++qq) {                                                   \
    int fidx = t * 2 + qq;                                                           \
    int r = fidx >> 2;                                                               \
    int jc = (fidx & 3) * 4;                                                         \
    int arow_ = (AROWEXPR);                                                          \
    float4 va = *(const float4*)((APTR) + (size_t)arow_ * HH + k0 + jc);             \
    As[jc + 0][r] = va.x; As[jc + 1][r] = va.y;                                      \
    As[jc + 2][r] = va.z; As[jc + 3][r] = va.w;                                      \
    int brow_ = (BROWEXPR);                                                          \
    float4 vb = *(const float4*)((BPTR) + (size_t)brow_ * HH + k0 + jc);             \
    Bs[jc + 0][r] = vb.x; Bs[jc + 1][r] = vb.y;                                      \
    Bs[jc + 2][r] = vb.z; Bs[jc + 3][r] = vb.w;                                      \
  }

#define GEMM_INNER                                                                   \
  _Pragma("unroll")                                                                  \
  for (int k = 0; k < BK; ++k) {                                                     \
    float av[8], bv[8];                                                              \
    *(float4*)&av[0] = *(const float4*)&As[k][ty * 4];                               \
    *(float4*)&av[4] = *(const float4*)&As[k][64 + ty * 4];                          \
    *(float4*)&bv[0] = *(const float4*)&Bs[k][tx * 4];                               \
    *(float4*)&bv[4] = *(const float4*)&Bs[k][64 + tx * 4];                          \
    _Pragma("unroll")                                                                \
    for (int i = 0; i < 8; ++i)                                                      \
      _Pragma("unroll")                                                              \
      for (int j = 0; j < 8; ++j)                                                    \
        acc[i][j] += av[i] * bv[j];                                                  \
  }

// q/k projection with row gather; epilogue writes fragment-major bf16 hi/lo.
__global__ __launch_bounds__(256) void proj_kernel(
    const float* __restrict__ clause,
    const int* __restrict__ pos_idx, const int* __restrict__ neg_idx,
    const float* __restrict__ WQ, const float* __restrict__ bQ,
    const float* __restrict__ WK, const float* __restrict__ bK,
    u16* __restrict__ qhi, u16* __restrict__ qlo,
    u16* __restrict__ khi, u16* __restrict__ klo) {
  const int* __restrict__ idx = blockIdx.z ? neg_idx : pos_idx;
  const float* __restrict__ W = blockIdx.z ? WK : WQ;
  const float* __restrict__ bias = blockIdx.z ? bK : bQ;
  u16* __restrict__ ohi = blockIdx.z ? khi : qhi;
  u16* __restrict__ olo = blockIdx.z ? klo : qlo;

  __shared__ float As[BK][BM];
  __shared__ float Bs[BK][BM];
  const int t = threadIdx.x;
  const int tx = t & 15, ty = t >> 4;
  const int row0 = blockIdx.x * BM;
  const int col0 = blockIdx.y * BM;
  float acc[8][8] = {};
  for (int k0 = 0; k0 < HH; k0 += BK) {
    GEMM_LOAD_TILE(clause, idx[row0 + r], W, col0 + r)
    __syncthreads();
    GEMM_INNER
    __syncthreads();
  }
#pragma unroll
  for (int i = 0; i < 8; ++i) {
    int rl = (i < 4) ? (ty * 4 + i) : (64 + ty * 4 + i - 4);
    int grow = row0 + rl;
    int Rf = grow >> 4, rl16 = grow & 15;
#pragma unroll
    for (int jh = 0; jh < 2; ++jh) {
      int c = col0 + jh * 64 + tx * 4;
      int Kf = c >> 5;
      int lane16 = rl16 + ((c & 31) >> 3) * 16;
      int sub = c & 7;
      size_t flat = ((size_t)(Rf * 16 + Kf)) * 512 + (size_t)lane16 * 8 + sub;
      ushort4 hv, lv;
      float v;
      v = acc[i][jh * 4 + 0] + bias[c + 0]; hv.x = f2bf(v); lv.x = f2bf(v - bf2f(hv.x));
      v = acc[i][jh * 4 + 1] + bias[c + 1]; hv.y = f2bf(v); lv.y = f2bf(v - bf2f(hv.y));
      v = acc[i][jh * 4 + 2] + bias[c + 2]; hv.z = f2bf(v); lv.z = f2bf(v - bf2f(hv.z));
      v = acc[i][jh * 4 + 3] + bias[c + 3]; hv.w = f2bf(v); lv.w = f2bf(v - bf2f(hv.w));
      *(ushort4*)(ohi + flat) = hv;
      *(ushort4*)(olo + flat) = lv;
    }
  }
}

// ---------------------------------------------------------------------------
// MFMA macros: pass-outer interleave (16 independent MFMAs between each
// dependent accumulate on the same acc[i][j]); pass order hh, hl, lh is
// preserved so results stay bit-identical to the 3-chain form.
#define MFMA16(A, B)                                                                 \
  _Pragma("unroll") for (int i_ = 0; i_ < 4; ++i_)                                   \
  _Pragma("unroll") for (int j_ = 0; j_ < 4; ++j_)                                   \
    acc[i_][j_] = __builtin_amdgcn_mfma_f32_16x16x32_bf16(A[i_], B[j_], acc[i_][j_], 0, 0, 0);

#define MFMAS(AH, AL, BH, BL)                                                        \
  do { MFMA16(AH, BH) MFMA16(AH, BL) MFMA16(AL, BH) } while (0)

#define LOADF(s, AH, AL, BH, BL, PAH, PAL, PBH, PBL)                                 \
  do {                                                                               \
    _Pragma("unroll") for (int f_ = 0; f_ < 4; ++f_) {                               \
      size_t oa_ = abase + (size_t)f_ * 8192 + (size_t)(s) * 512;                    \
      size_t ob_ = bbase + (size_t)f_ * 8192 + (size_t)(s) * 512;                    \
      AH[f_] = *(const bf16x8*)(PAH + oa_);                                          \
      AL[f_] = *(const bf16x8*)(PAL + oa_);                                          \
      BH[f_] = *(const bf16x8*)(PBH + ob_);                                          \
      BL[f_] = *(const bf16x8*)(PBL + ob_);                                          \
    }                                                                                \
  } while (0)

// ---------------------------------------------------------------------------
// K_t GEMM (lit @ varKw.T) via MFMA on pre-split fragments; tanh epilogue.
__global__ __launch_bounds__(256, 2) void ktu_kernel(
    const u16* __restrict__ lithi, const u16* __restrict__ litlo,
    const u16* __restrict__ wkhi, const u16* __restrict__ wklo,
    const float* __restrict__ tvec, const float* __restrict__ attnw,
    float* __restrict__ upart) {
  const int t = threadIdx.x, lane = t & 63, wid = t >> 6;
  const int wn = wid & 1, wm = wid >> 1;
  const int row0 = blockIdx.x * 128;
  const size_t abase = (size_t)((row0 >> 4) + wn * 4) * 8192 + (size_t)lane * 8;
  const size_t bbase = (size_t)(blockIdx.y * 8 + wm * 4) * 8192 + (size_t)lane * 8;

  f32x4 acc[4][4] = {};
  bf16x8 aH0[4], aL0[4], bH0[4], bL0[4];
  bf16x8 aH1[4], aL1[4], bH1[4], bL1[4];
  LOADF(0, aH0, aL0, bH0, bL0, lithi, litlo, wkhi, wklo);
#pragma unroll
  for (int s = 0; s < 16; s += 2) {
    LOADF(s + 1, aH1, aL1, bH1, bL1, lithi, litlo, wkhi, wklo);
    MFMAS(aH0, aL0, bH0, bL0);
    if (s + 2 < 16) LOADF(s + 2, aH0, aL0, bH0, bL0, lithi, litlo, wkhi, wklo);
    MFMAS(aH1, aL1, bH1, bL1);
  }

  // epilogue: u partial = sum_c tanh(K_t + tvec[c]) * attnw[c]
  const int cbase = blockIdx.y * 128 + wm * 64;
  float tv[4], aw[4];
#pragma unroll
  for (int j = 0; j < 4; ++j) {
    int c = cbase + j * 16 + (lane & 15);
    tv[j] = tvec[c]; aw[j] = attnw[c];
  }
  float us[4][4];
#pragma unroll
  for (int i = 0; i < 4; ++i)
#pragma unroll
    for (int r = 0; r < 4; ++r) {
      float s = 0.f;
#pragma unroll
      for (int j = 0; j < 4; ++j) {
        float x = acc[i][j][r] + tv[j];
        float th = 1.0f - 2.0f / (__expf(2.0f * x) + 1.0f);   // safe tanh
        s += th * aw[j];
      }
      us[i][r] = s;
    }
#pragma unroll
  for (int m = 1; m < 16; m <<= 1)
#pragma unroll
    for (int i = 0; i < 4; ++i)
#pragma unroll
      for (int r = 0; r < 4; ++r) us[i][r] += __shfl_xor(us[i][r], m, 64);
  if ((lane & 15) == 0) {
#pragma unroll
    for (int i = 0; i < 4; ++i)
#pragma unroll
      for (int r = 0; r < 4; ++r) {
        int row = row0 + wn * 64 + i * 16 + (lane >> 4) * 4 + r;
        upart[(size_t)(blockIdx.y * 2 + wm) * NVARS + row] = us[i][r];
      }
  }
}

// ---------------------------------------------------------------------------
// scores = q @ k.T / sqrt(H) via split-bf16 MFMA, fragment-major global reads,
// no LDS staging; XCD-supertile swizzle keeps each XCD's concurrent blocks in
// one 8x8 supertile (8 A panels + 8 B panels = 4 MB = one XCD's L2).
__global__ __launch_bounds__(256, 2) void scores_kernel(
    const u16* __restrict__ qhi, const u16* __restrict__ qlo,
    const u16* __restrict__ khi, const u16* __restrict__ klo,
    const unsigned long long* __restrict__ vmask, SPart* __restrict__ parts) {
  __shared__ unsigned long long mrow[128][2];
  __shared__ float s_rv[4]; __shared__ int s_ri[4]; __shared__ float s_rs[4];
  __shared__ float s_bm; __shared__ int s_ba;

  const int t = threadIdx.x;
  const int lane = t & 63;
  const int wid = t >> 6;
  const int wn = wid & 1, wm = wid >> 1;

  // XCD supertile swizzle (bijective on [0,1024))
  const int bid = blockIdx.x;
  const int xcd = bid & 7, p = bid >> 3;
  const int sp = p >> 6, q = p & 63;
  const int g = xcd * 2 + sp;                 // supertile id [0,16)
  const int bx = (g & 3) * 8 + (q & 7);
  const int by = (g >> 2) * 8 + (q >> 3);

  const int n0 = by * 128;   // q rows
  const int m0 = bx * 128;   // k rows
  const size_t abase = (size_t)((n0 >> 4) + wn * 4) * 8192 + (size_t)lane * 8;
  const size_t bbase = (size_t)((m0 >> 4) + wm * 4) * 8192 + (size_t)lane * 8;

  // stage masks early (latency hidden under MFMA loop)
  {
    int r = t >> 1, w = t & 1;
    mrow[r][w] = vmask[(size_t)(n0 + r) * (NMS / 64) + (m0 >> 6) + w];
  }
  __syncthreads();

  f32x4 acc[4][4] = {};
  bf16x8 aH0[4], aL0[4], bH0[4], bL0[4];
  bf16x8 aH1[4], aL1[4], bH1[4], bL1[4];
  LOADF(0, aH0, aL0, bH0, bL0, qhi, qlo, khi, klo);
#pragma unroll
  for (int s = 0; s < 16; s += 2) {
    LOADF(s + 1, aH1, aL1, bH1, bL1, qhi, qlo, khi, klo);
    MFMAS(aH0, aL0, bH0, bL0);
    if (s + 2 < 16) LOADF(s + 2, aH0, aL0, bH0, bL0, qhi, qlo, khi, klo);
    MFMAS(aH1, aL1, bH1, bL1);
  }

  // C/D layout: col = lane&15, row = (lane>>4)*4 + reg
  const int rbase = wn * 64 + (lane >> 4) * 4;
  const int cb15 = (lane & 15);

  float mv = NEGV; int mi = 0x7fffffff;
#pragma unroll
  for (int i = 0; i < 4; ++i) {
#pragma unroll
    for (int r = 0; r < 4; ++r) {
      int rl = rbase + i * 16 + r;
      unsigned long long ww = mrow[rl][wm];
      int gb = (n0 + rl) * NMS + m0;
#pragma unroll
      for (int j = 0; j < 4; ++j) {
        int bit = j * 16 + cb15;
        int cl = wm * 64 + bit;
        float sv = acc[i][j][r] * RSQRT_H;
        acc[i][j][r] = sv;
        bool valid = ((ww >> bit) & 1ull) != 0;
        if (valid && (sv > mv || (sv == mv && gb + cl < mi))) { mv = sv; mi = gb + cl; }
      }
    }
  }
  wreduce_maxidx(mv, mi);
  if ((t & 63) == 0) { s_rv[wid] = mv; s_ri[wid] = mi; }
  __syncthreads();
  if (t == 0) {
    float bm = s_rv[0]; int ba = s_ri[0];
    for (int w = 1; w < 4; ++w)
      if (s_rv[w] > bm || (s_rv[w] == bm && s_ri[w] < ba)) { bm = s_rv[w]; ba = s_ri[w]; }
    s_bm = bm; s_ba = ba;
  }
  __syncthreads();
  const float bm = s_bm;

  float se = 0.f;
#pragma unroll
  for (int i = 0; i < 4; ++i) {
#pragma unroll
    for (int r = 0; r < 4; ++r) {
      int rl = rbase + i * 16 + r;
      unsigned long long ww = mrow[rl][wm];
#pragma unroll
      for (int j = 0; j < 4; ++j) {
        int bit = j * 16 + cb15;
        bool valid = ((ww >> bit) & 1ull) != 0;
        if (valid) se += __expf(acc[i][j][r] - bm);
      }
    }
  }
  se = wreduce_sum(se);
  if ((t & 63) == 0) s_rs[wid] = se;
  __syncthreads();
  if (t == 0) {
    SPart pt;
    pt.m = s_bm;
    pt.s = s_rs[0] + s_rs[1] + s_rs[2] + s_rs[3];
    pt.a = s_ba; pt.pad = 0;
    parts[by * 32 + bx] = pt;
  }
}

// ---------------------------------------------------------------------------
// Final combine.  d_out is FLOAT32 x4: {c_logp, pos_idx[ci], neg_idx[cj], var_idx}.
__global__ __launch_bounds__(256) void final_kernel(
    const float* __restrict__ upart, const SPart* __restrict__ parts,
    const int* __restrict__ pos_idx, const int* __restrict__ neg_idx,
    float* __restrict__ out) {
  __shared__ float s_rv[4]; __shared__ int s_ri[4]; __shared__ float s_rs[4];
  __shared__ float s_umax; __shared__ int s_uarg; __shared__ float s_usum;
  __shared__ float s_gm; __shared__ int s_ga;
  const int t = threadIdx.x;

  float mv = -1.0e38f; int mi = 0x7fffffff;
  for (int i = t; i < NVARS; i += 256) {
    float u = 0.f;
#pragma unroll
    for (int p = 0; p < 8; ++p) u += upart[(size_t)p * NVARS + i];
    if (u > mv || (u == mv && i < mi)) { mv = u; mi = i; }
  }
  wreduce_maxidx(mv, mi);
  if ((t & 63) == 0) { s_rv[t >> 6] = mv; s_ri[t >> 6] = mi; }
  __syncthreads();
  if (t == 0) {
    float bm = s_rv[0]; int ba = s_ri[0];
    for (int w = 1; w < 4; ++w)
      if (s_rv[w] > bm || (s_rv[w] == bm && s_ri[w] < ba)) { bm = s_rv[w]; ba = s_ri[w]; }
    s_umax = bm; s_uarg = ba;
  }
  __syncthreads();
  const float umax = s_umax;
  float se = 0.f;
  for (int i = t; i < NVARS; i += 256) {
    float u = 0.f;
#pragma unroll
    for (int p = 0; p < 8; ++p) u += upart[(size_t)p * NVARS + i];
    se += __expf(u - umax);
  }
  se = wreduce_sum(se);
  if ((t & 63) == 0) s_rs[t >> 6] = se;
  __syncthreads();
  if (t == 0) s_usum = s_rs[0] + s_rs[1] + s_rs[2] + s_rs[3];
  __syncthreads();

  mv = NEGV; mi = 0x7fffffff;
  for (int i = t; i < 1024; i += 256) {
    SPart p = parts[i];
    if (p.m > mv || (p.m == mv && p.a < mi)) { mv = p.m; mi = p.a; }
  }
  wreduce_maxidx(mv, mi);
  if ((t & 63) == 0) { s_rv[t >> 6] = mv; s_ri[t >> 6] = mi; }
  __syncthreads();
  if (t == 0) {
    float bm = s_rv[0]; int ba = s_ri[0];
    for (int w = 1; w < 4; ++w)
      if (s_rv[w] > bm || (s_rv[w] == bm && s_ri[w] < ba)) { bm = s_rv[w]; ba = s_ri[w]; }
    s_gm = bm; s_ga = ba;
  }
  __syncthreads();
  const float gm = s_gm;
  float ss = 0.f;
  for (int i = t; i < 1024; i += 256) {
    SPart p = parts[i];
    ss += p.s * __expf(p.m - gm);
  }
  ss = wreduce_sum(ss);
  if ((t & 63) == 0) s_rs[t >> 6] = ss;
  __syncthreads();
  if (t == 0) {
    float gsum = s_rs[0] + s_rs[1] + s_rs[2] + s_rs[3];
    float c_logp = -logf(gsum) - logf(s_usum);
    int ga = s_ga;
    if (ga == 0x7fffffff) ga = 0;
    int ci = ga >> 12, cj = ga & 4095;
    out[0] = c_logp;
    out[1] = (float)pos_idx[ci];
    out[2] = (float)neg_idx[cj];
    out[3] = (float)s_uarg;
  }
}

extern "C" void kernel_launch(void* const* d_in, const int* in_sizes, int n_in,
                              void* d_out, int out_size, void* d_ws, size_t ws_size,
                              hipStream_t stream) {
  (void)in_sizes; (void)n_in; (void)out_size; (void)ws_size;
  const float* lit    = (const float*)d_in[0];
  const float* clause = (const float*)d_in[1];
  const int* pos_idx  = (const int*)d_in[2];
  const int* neg_idx  = (const int*)d_in[3];
  const void* keep    = d_in[4];
  const void* taken   = d_in[5];
  const float* varKw  = (const float*)d_in[6];
  const float* varKb  = (const float*)d_in[7];
  const float* varQw  = (const float*)d_in[8];
  const float* varQb  = (const float*)d_in[9];
  const float* attnw  = (const float*)d_in[10];
  // d_in[11] var_attn_b: uniform shift, cancels in log_softmax max/argmax
  const float* WQw    = (const float*)d_in[12];
  const float* WQb    = (const float*)d_in[13];
  const float* WKw    = (const float*)d_in[14];
  const float* WKb    = (const float*)d_in[15];

  char* ws = (char*)d_ws;
  size_t off = 0;
  auto alloc = [&](size_t b) {
    char* p = ws + off;
    off = (off + b + 255) & ~(size_t)255;
    return p;
  };
  int* flag                  = (int*)alloc(4);
  double* qpart              = (double*)alloc((size_t)1024 * HH * 8);
  double* Qd                 = (double*)alloc(HH * 8);
  float* tvec                = (float*)alloc(HH * 4);
  float* upart               = (float*)alloc(8 * (size_t)NVARS * 4);
  unsigned long long* vmask  = (unsigned long long*)alloc((size_t)NPOS * (NMS / 64) * 8);
  u16* qhi                   = (u16*)alloc((size_t)NPOS * HH * 2);
  u16* qlo                   = (u16*)alloc((size_t)NPOS * HH * 2);
  u16* khi                   = (u16*)alloc((size_t)NMS * HH * 2);
  u16* klo                   = (u16*)alloc((size_t)NMS * HH * 2);
  u16* wkhi                  = (u16*)alloc((size_t)HH * HH * 2);
  u16* wklo                  = (u16*)alloc((size_t)HH * HH * 2);
  u16* lithi                 = (u16*)alloc((size_t)NVARS * HH * 2);
  u16* litlo                 = (u16*)alloc((size_t)NVARS * HH * 2);
  SPart* parts               = (SPart*)alloc(1024 * sizeof(SPart));

  detect_kernel<<<1, 64, 0, stream>>>((const unsigned int*)keep, flag);
  pack_kernel<<<16384, 256, 0, stream>>>(keep, taken, flag, vmask);
  qsum_kernel<<<512, 256, 0, stream>>>(clause, qpart);
  qred_kernel<<<32, 256, 0, stream>>>(qpart, Qd);
  prepmv_kernel<<<32, 256, 0, stream>>>(Qd, varQw, varQb, varKb, tvec);
  tofrag_kernel<<<128, 256, 0, stream>>>(varKw, wkhi, wklo);
  tofrag_kernel<<<4096, 256, 0, stream>>>(lit, lithi, litlo);
  proj_kernel<<<dim3(32, 4, 2), 256, 0, stream>>>(clause, pos_idx, neg_idx,
                                                  WQw, WQb, WKw, WKb,
                                                  qhi, qlo, khi, klo);
  ktu_kernel<<<dim3(128, 4), 256, 0, stream>>>(lithi, litlo, wkhi, wklo,
                                               tvec, attnw, upart);
  scores_kernel<<<1024, 256, 0, stream>>>(qhi, qlo, khi, klo, vmask, parts);
  final_kernel<<<1, 256, 0, stream>>>(upart, parts, pos_idx, neg_idx,
                                      (float*)d_out);
}

// Round 6
// 262.046 us; speedup vs baseline: 2.1449x; 1.2240x over previous
//
#include <hip/hip_runtime.h>
#include <hip/hip_bf16.h>
#include <math.h>

#define HH 512
#define NVARS 16384
#define NPOS 4096
#define NMS 4096
#define NEGV -1.0e30f
#define RSQRT_H 0.04419417382415922f   // 1/sqrt(512)

#define BM 128
#define BK 16

typedef unsigned short u16;
typedef __attribute__((ext_vector_type(8))) short bf16x8;
typedef __attribute__((ext_vector_type(4))) float f32x4;

struct SPart { float m; float s; int a; int pad; };

__device__ inline u16 f2bf(float f) {
  unsigned u = __float_as_uint(f);
  unsigned r = (u + 0x7fffu + ((u >> 16) & 1u)) >> 16;
  return (u16)r;
}
__device__ inline float bf2f(u16 h) { return __uint_as_float(((unsigned)h) << 16); }

__device__ inline void wreduce_maxidx(float& v, int& idx) {
#pragma unroll
  for (int m = 1; m < 64; m <<= 1) {
    float ov = __shfl_xor(v, m, 64);
    int oi = __shfl_xor(idx, m, 64);
    if (ov > v || (ov == v && oi < idx)) { v = ov; idx = oi; }
  }
}

__device__ inline float wreduce_sum(float v) {
#pragma unroll
  for (int m = 1; m < 64; m <<= 1) v += __shfl_xor(v, m, 64);
  return v;
}

// ---------------------------------------------------------------------------
__global__ void detect_kernel(const unsigned int* __restrict__ keep, int* __restrict__ flag) {
  if (threadIdx.x == 0 && blockIdx.x == 0) {
    int ok = 1;
    for (int i = 0; i < 64; ++i) if (keep[i] > 1u) ok = 0;
    *flag = ok;   // 1: int32 masks, 0: byte masks
  }
}

// Pack valid = keep & ~taken into 64-bit words via LDS nibble assembly.
// Each thread handles 4 consecutive elements (vector loads).
__global__ __launch_bounds__(256) void pack_kernel(
    const void* __restrict__ keep, const void* __restrict__ taken,
    const int* __restrict__ flag, unsigned long long* __restrict__ vmask) {
  __shared__ unsigned char nib[256];
  const int f = *flag;
  const int t = threadIdx.x;
  const size_t e = (size_t)blockIdx.x * 1024 + (size_t)t * 4;
  int v0, v1, v2, v3;
  if (f) {
    uint4 kv = *(const uint4*)((const unsigned int*)keep + e);
    uint4 tv = *(const uint4*)((const unsigned int*)taken + e);
    v0 = kv.x && !tv.x; v1 = kv.y && !tv.y; v2 = kv.z && !tv.z; v3 = kv.w && !tv.w;
  } else {
    unsigned kv = *(const unsigned*)((const unsigned char*)keep + e);
    unsigned tv = *(const unsigned*)((const unsigned char*)taken + e);
    v0 = (kv & 0xffu) && !(tv & 0xffu);
    v1 = (kv & 0xff00u) && !(tv & 0xff00u);
    v2 = (kv & 0xff0000u) && !(tv & 0xff0000u);
    v3 = (kv & 0xff000000u) && !(tv & 0xff000000u);
  }
  nib[t] = (unsigned char)(v0 | (v1 << 1) | (v2 << 2) | (v3 << 3));
  __syncthreads();
  if (t < 16) {
    unsigned long long m = 0;
#pragma unroll
    for (int j = 0; j < 16; ++j)
      m |= (unsigned long long)nib[t * 16 + j] << (4 * j);
    vmask[(size_t)blockIdx.x * 16 + t] = m;
  }
}

// ---------------------------------------------------------------------------
// Q partial sums; float4 loads (16B/lane), 2 row-halves x 128 col-groups.
__global__ __launch_bounds__(256) void qsum_kernel(
    const float* __restrict__ clause, double* __restrict__ qpart) {
  const int b = blockIdx.x, t = threadIdx.x;
  const int fg = t & 127;
  const int rh = t >> 7;
  const float* base = clause + (size_t)(b * 128 + rh * 64) * HH + fg * 4;
  double a0 = 0.0, a1 = 0.0, a2 = 0.0, a3 = 0.0;
#pragma unroll 4
  for (int r = 0; r < 64; ++r) {
    float4 v = *(const float4*)(base + (size_t)r * HH);
    a0 += (double)v.x; a1 += (double)v.y; a2 += (double)v.z; a3 += (double)v.w;
  }
  double* o = qpart + (size_t)(b * 2 + rh) * HH + fg * 4;
  o[0] = a0; o[1] = a1; o[2] = a2; o[3] = a3;
}

// reduce 1024 partial Q vectors -> Qd[512] (f64)
__global__ __launch_bounds__(256) void qred_kernel(
    const double* __restrict__ qpart, double* __restrict__ Qd) {
  __shared__ double red[256];
  const int t = threadIdx.x;
  const int h = blockIdx.x * 16 + (t & 15);
  const int chunk = t >> 4;
  double s = 0.0;
  for (int j = 0; j < 64; ++j) s += qpart[(size_t)(chunk * 64 + j) * HH + h];
  red[t] = s;
  __syncthreads();
  for (int off = 8; off > 0; off >>= 1) {
    if (chunk < off) red[t] += red[t + off * 16];
    __syncthreads();
  }
  if (t < 16) Qd[blockIdx.x * 16 + t] = red[t];
}

// tvec[h] = (Q @ var_Q_w.T)[h] + var_Q_b[h] + var_K_b[h]
__global__ __launch_bounds__(256) void prepmv_kernel(
    const double* __restrict__ Qd, const float* __restrict__ varQw,
    const float* __restrict__ varQb, const float* __restrict__ varKb,
    float* __restrict__ tvec) {
  __shared__ double red[256];
  const int t = threadIdx.x;
  const int h = blockIdx.x * 16 + (t & 15);
  const int chunk = t >> 4;
  const float* wrow = varQw + (size_t)h * HH + chunk * 32;
  const double* qd = Qd + chunk * 32;
  double s = 0.0;
  for (int j = 0; j < 32; ++j) s += qd[j] * (double)wrow[j];
  red[t] = s;
  __syncthreads();
  for (int off = 8; off > 0; off >>= 1) {
    if (chunk < off) red[t] += red[t + off * 16];
    __syncthreads();
  }
  if (t < 16) {
    int hh = blockIdx.x * 16 + t;
    tvec[hh] = (float)(red[t] + (double)varQb[hh] + (double)varKb[hh]);
  }
}

// ---------------------------------------------------------------------------
// convert a row-major f32 matrix [nrow x 512] into fragment-major bf16 hi/lo.
// frag f: rows (f>>4)*16..+16, cols (f&15)*32..+32; lane l holds row (l&15),
// k-chunk (l>>4)*8. flat addr = f*512 + lane*8.
__global__ __launch_bounds__(256) void tofrag_kernel(
    const float* __restrict__ src, u16* __restrict__ hi, u16* __restrict__ lo) {
  const int frag = blockIdx.x * 4 + (threadIdx.x >> 6);
  const int lane = threadIdx.x & 63;
  const int R = frag >> 4, K = frag & 15;
  const float* p = src + (size_t)(R * 16 + (lane & 15)) * HH + K * 32 + (lane >> 4) * 8;
  float v[8];
  *(float4*)&v[0] = *(const float4*)p;
  *(float4*)&v[4] = *(const float4*)(p + 4);
  u16 h[8], l[8];
#pragma unroll
  for (int e = 0; e < 8; ++e) { h[e] = f2bf(v[e]); l[e] = f2bf(v[e] - bf2f(h[e])); }
  size_t base = (size_t)frag * 512 + (size_t)lane * 8;
  *(ushort4*)(hi + base) = *(ushort4*)&h[0];
  *(ushort4*)(hi + base + 4) = *(ushort4*)&h[4];
  *(ushort4*)(lo + base) = *(ushort4*)&l[0];
  *(ushort4*)(lo + base + 4) = *(ushort4*)&l[4];
}

// ---------------------------------------------------------------------------
// MFMA macros: pass-outer interleave; pass order hh, hl, lh preserved.
#define MFMA16(A, B)                                                                 \
  _Pragma("unroll") for (int i_ = 0; i_ < 4; ++i_)                                   \
  _Pragma("unroll") for (int j_ = 0; j_ < 4; ++j_)                                   \
    acc[i_][j_] = __builtin_amdgcn_mfma_f32_16x16x32_bf16(A[i_], B[j_], acc[i_][j_], 0, 0, 0);

#define MFMAS(AH, AL, BH, BL)                                                        \
  do { MFMA16(AH, BH) MFMA16(AH, BL) MFMA16(AL, BH) } while (0)

#define LOADF(s, AH, AL, BH, BL, PAH, PAL, PBH, PBL)                                 \
  do {                                                                               \
    _Pragma("unroll") for (int f_ = 0; f_ < 4; ++f_) {                               \
      size_t oa_ = abase + (size_t)f_ * 8192 + (size_t)(s) * 512;                    \
      size_t ob_ = bbase + (size_t)f_ * 8192 + (size_t)(s) * 512;                    \
      AH[f_] = *(const bf16x8*)(PAH + oa_);                                          \
      AL[f_] = *(const bf16x8*)(PAL + oa_);                                          \
      BH[f_] = *(const bf16x8*)(PBH + ob_);                                          \
      BL[f_] = *(const bf16x8*)(PBL + ob_);                                          \
    }                                                                                \
  } while (0)

// ---------------------------------------------------------------------------
// q/k projection as 3-pass split-bf16 MFMA with on-the-fly A gather+split.
// Writes row-major f32 (split to fragments by tofrag afterwards).
__global__ __launch_bounds__(256, 3) void proj_kernel(
    const float* __restrict__ clause,
    const int* __restrict__ pos_idx, const int* __restrict__ neg_idx,
    const u16* __restrict__ wqhi, const u16* __restrict__ wqlo,
    const u16* __restrict__ wkhi2, const u16* __restrict__ wklo2,
    const float* __restrict__ bQ, const float* __restrict__ bK,
    float* __restrict__ qmat, float* __restrict__ kmat) {
  const int* __restrict__ idx = blockIdx.z ? neg_idx : pos_idx;
  const u16* __restrict__ bhp = blockIdx.z ? wkhi2 : wqhi;
  const u16* __restrict__ blp = blockIdx.z ? wklo2 : wqlo;
  const float* __restrict__ bias = blockIdx.z ? bK : bQ;
  float* __restrict__ out = blockIdx.z ? kmat : qmat;

  const int t = threadIdx.x, lane = t & 63, wid = t >> 6;
  const int wn = wid & 1, wm = wid >> 1;
  const int row0 = blockIdx.x * 128;
  const int col0 = blockIdx.y * 128;

  const float* aptr[4];
#pragma unroll
  for (int f = 0; f < 4; ++f) {
    int g = idx[row0 + wn * 64 + f * 16 + (lane & 15)];
    aptr[f] = clause + (size_t)g * HH + (lane >> 4) * 8;
  }
  const size_t bbase = (size_t)((col0 >> 4) + wm * 4) * 8192 + (size_t)lane * 8;

  f32x4 acc[4][4] = {};
#pragma unroll
  for (int s = 0; s < 16; ++s) {
    float rA[4][8];
    bf16x8 aH[4], aL[4], bH[4], bL[4];
#pragma unroll
    for (int f = 0; f < 4; ++f) {
      *(float4*)&rA[f][0] = *(const float4*)(aptr[f] + s * 32);
      *(float4*)&rA[f][4] = *(const float4*)(aptr[f] + s * 32 + 4);
      size_t ob = bbase + (size_t)f * 8192 + (size_t)s * 512;
      bH[f] = *(const bf16x8*)(bhp + ob);
      bL[f] = *(const bf16x8*)(blp + ob);
    }
#pragma unroll
    for (int f = 0; f < 4; ++f)
#pragma unroll
      for (int e = 0; e < 8; ++e) {
        float v = rA[f][e];
        u16 h = f2bf(v);
        aH[f][e] = (short)h;
        aL[f][e] = (short)f2bf(v - bf2f(h));
      }
    MFMAS(aH, aL, bH, bL);
  }

#pragma unroll
  for (int i = 0; i < 4; ++i)
#pragma unroll
    for (int j = 0; j < 4; ++j) {
      int h = col0 + wm * 64 + j * 16 + (lane & 15);
      float b = bias[h];
#pragma unroll
      for (int r = 0; r < 4; ++r) {
        int n = row0 + wn * 64 + i * 16 + (lane >> 4) * 4 + r;
        out[(size_t)n * HH + h] = acc[i][j][r] + b;
      }
    }
}

// ---------------------------------------------------------------------------
// K_t GEMM (lit @ varKw.T) via MFMA on pre-split fragments; tanh epilogue.
// Simple per-stage loop; latency hidden by TLP (3 waves/SIMD).
__global__ __launch_bounds__(256, 3) void ktu_kernel(
    const u16* __restrict__ lithi, const u16* __restrict__ litlo,
    const u16* __restrict__ wkhi, const u16* __restrict__ wklo,
    const float* __restrict__ tvec, const float* __restrict__ attnw,
    float* __restrict__ upart) {
  const int t = threadIdx.x, lane = t & 63, wid = t >> 6;
  const int wn = wid & 1, wm = wid >> 1;
  const int row0 = blockIdx.x * 128;
  const size_t abase = (size_t)((row0 >> 4) + wn * 4) * 8192 + (size_t)lane * 8;
  const size_t bbase = (size_t)(blockIdx.y * 8 + wm * 4) * 8192 + (size_t)lane * 8;

  f32x4 acc[4][4] = {};
#pragma unroll
  for (int s = 0; s < 16; ++s) {
    bf16x8 aH[4], aL[4], bH[4], bL[4];
    LOADF(s, aH, aL, bH, bL, lithi, litlo, wkhi, wklo);
    MFMAS(aH, aL, bH, bL);
  }

  const int cbase = blockIdx.y * 128 + wm * 64;
  float tv[4], aw[4];
#pragma unroll
  for (int j = 0; j < 4; ++j) {
    int c = cbase + j * 16 + (lane & 15);
    tv[j] = tvec[c]; aw[j] = attnw[c];
  }
  float us[4][4];
#pragma unroll
  for (int i = 0; i < 4; ++i)
#pragma unroll
    for (int r = 0; r < 4; ++r) {
      float s = 0.f;
#pragma unroll
      for (int j = 0; j < 4; ++j) {
        float x = acc[i][j][r] + tv[j];
        float th = 1.0f - 2.0f / (__expf(2.0f * x) + 1.0f);   // safe tanh
        s += th * aw[j];
      }
      us[i][r] = s;
    }
#pragma unroll
  for (int m = 1; m < 16; m <<= 1)
#pragma unroll
    for (int i = 0; i < 4; ++i)
#pragma unroll
      for (int r = 0; r < 4; ++r) us[i][r] += __shfl_xor(us[i][r], m, 64);
  if ((lane & 15) == 0) {
#pragma unroll
    for (int i = 0; i < 4; ++i)
#pragma unroll
      for (int r = 0; r < 4; ++r) {
        int row = row0 + wn * 64 + i * 16 + (lane >> 4) * 4 + r;
        upart[(size_t)(blockIdx.y * 2 + wm) * NVARS + row] = us[i][r];
      }
  }
}

// ---------------------------------------------------------------------------
// scores = q @ k.T / sqrt(H): 3-pass split-bf16 MFMA, fragment-major global
// reads, no LDS staging, XCD supertile swizzle; TLP-based latency hiding.
__global__ __launch_bounds__(256, 3) void scores_kernel(
    const u16* __restrict__ qhi, const u16* __restrict__ qlo,
    const u16* __restrict__ khi, const u16* __restrict__ klo,
    const unsigned long long* __restrict__ vmask, SPart* __restrict__ parts) {
  __shared__ unsigned long long mrow[128][2];
  __shared__ float s_rv[4]; __shared__ int s_ri[4]; __shared__ float s_rs[4];
  __shared__ float s_bm; __shared__ int s_ba;

  const int t = threadIdx.x;
  const int lane = t & 63;
  const int wid = t >> 6;
  const int wn = wid & 1, wm = wid >> 1;

  // XCD supertile swizzle (bijective on [0,1024))
  const int bid = blockIdx.x;
  const int xcd = bid & 7, p = bid >> 3;
  const int sp = p >> 6, q = p & 63;
  const int g = xcd * 2 + sp;
  const int bx = (g & 3) * 8 + (q & 7);
  const int by = (g >> 2) * 8 + (q >> 3);

  const int n0 = by * 128;
  const int m0 = bx * 128;
  const size_t abase = (size_t)((n0 >> 4) + wn * 4) * 8192 + (size_t)lane * 8;
  const size_t bbase = (size_t)((m0 >> 4) + wm * 4) * 8192 + (size_t)lane * 8;

  {
    int r = t >> 1, w = t & 1;
    mrow[r][w] = vmask[(size_t)(n0 + r) * (NMS / 64) + (m0 >> 6) + w];
  }
  __syncthreads();

  f32x4 acc[4][4] = {};
#pragma unroll
  for (int s = 0; s < 16; ++s) {
    bf16x8 aH[4], aL[4], bH[4], bL[4];
    LOADF(s, aH, aL, bH, bL, qhi, qlo, khi, klo);
    MFMAS(aH, aL, bH, bL);
  }

  // C/D layout: col = lane&15, row = (lane>>4)*4 + reg
  const int rbase = wn * 64 + (lane >> 4) * 4;
  const int cb15 = (lane & 15);

  float mv = NEGV; int mi = 0x7fffffff;
#pragma unroll
  for (int i = 0; i < 4; ++i) {
#pragma unroll
    for (int r = 0; r < 4; ++r) {
      int rl = rbase + i * 16 + r;
      unsigned long long ww = mrow[rl][wm];
      int gb = (n0 + rl) * NMS + m0;
#pragma unroll
      for (int j = 0; j < 4; ++j) {
        int bit = j * 16 + cb15;
        int cl = wm * 64 + bit;
        float sv = acc[i][j][r] * RSQRT_H;
        acc[i][j][r] = sv;
        bool valid = ((ww >> bit) & 1ull) != 0;
        if (valid && (sv > mv || (sv == mv && gb + cl < mi))) { mv = sv; mi = gb + cl; }
      }
    }
  }
  wreduce_maxidx(mv, mi);
  if ((t & 63) == 0) { s_rv[wid] = mv; s_ri[wid] = mi; }
  __syncthreads();
  if (t == 0) {
    float bm = s_rv[0]; int ba = s_ri[0];
    for (int w = 1; w < 4; ++w)
      if (s_rv[w] > bm || (s_rv[w] == bm && s_ri[w] < ba)) { bm = s_rv[w]; ba = s_ri[w]; }
    s_bm = bm; s_ba = ba;
  }
  __syncthreads();
  const float bm = s_bm;

  float se = 0.f;
#pragma unroll
  for (int i = 0; i < 4; ++i) {
#pragma unroll
    for (int r = 0; r < 4; ++r) {
      int rl = rbase + i * 16 + r;
      unsigned long long ww = mrow[rl][wm];
#pragma unroll
      for (int j = 0; j < 4; ++j) {
        int bit = j * 16 + cb15;
        bool valid = ((ww >> bit) & 1ull) != 0;
        if (valid) se += __expf(acc[i][j][r] - bm);
      }
    }
  }
  se = wreduce_sum(se);
  if ((t & 63) == 0) s_rs[wid] = se;
  __syncthreads();
  if (t == 0) {
    SPart pt;
    pt.m = s_bm;
    pt.s = s_rs[0] + s_rs[1] + s_rs[2] + s_rs[3];
    pt.a = s_ba; pt.pad = 0;
    parts[by * 32 + bx] = pt;
  }
}

// ---------------------------------------------------------------------------
// u reduction stage 1: 64 blocks x 256 vars -> per-block {max, argmax, sumexp}.
__global__ __launch_bounds__(256) void usum_kernel(
    const float* __restrict__ upart, SPart* __restrict__ uparts2) {
  __shared__ float s_rv[4]; __shared__ int s_ri[4]; __shared__ float s_rs[4];
  __shared__ float s_bm; __shared__ int s_ba;
  const int t = threadIdx.x;
  const int i = blockIdx.x * 256 + t;
  float u = 0.f;
#pragma unroll
  for (int p = 0; p < 8; ++p) u += upart[(size_t)p * NVARS + i];
  float mv = u; int mi = i;
  wreduce_maxidx(mv, mi);
  if ((t & 63) == 0) { s_rv[t >> 6] = mv; s_ri[t >> 6] = mi; }
  __syncthreads();
  if (t == 0) {
    float bm = s_rv[0]; int ba = s_ri[0];
    for (int w = 1; w < 4; ++w)
      if (s_rv[w] > bm || (s_rv[w] == bm && s_ri[w] < ba)) { bm = s_rv[w]; ba = s_ri[w]; }
    s_bm = bm; s_ba = ba;
  }
  __syncthreads();
  float se = __expf(u - s_bm);
  se = wreduce_sum(se);
  if ((t & 63) == 0) s_rs[t >> 6] = se;
  __syncthreads();
  if (t == 0) {
    SPart p;
    p.m = s_bm;
    p.s = s_rs[0] + s_rs[1] + s_rs[2] + s_rs[3];
    p.a = s_ba; p.pad = 0;
    uparts2[blockIdx.x] = p;
  }
}

// ---------------------------------------------------------------------------
// Final combine.  d_out is FLOAT32 x4: {c_logp, pos_idx[ci], neg_idx[cj], var_idx}.
__global__ __launch_bounds__(256) void final_kernel(
    const SPart* __restrict__ uparts2, const SPart* __restrict__ parts,
    const int* __restrict__ pos_idx, const int* __restrict__ neg_idx,
    float* __restrict__ out) {
  __shared__ float s_rv[4]; __shared__ int s_ri[4]; __shared__ float s_rs[4];
  __shared__ float s_umax; __shared__ int s_uarg; __shared__ float s_usum;
  __shared__ float s_gm; __shared__ int s_ga;
  const int t = threadIdx.x;

  // --- u parts (64) ---
  float mv = -3.0e38f; int mi = 0x7fffffff;
  SPart up;
  if (t < 64) {
    up = uparts2[t];
    mv = up.m; mi = up.a;
  }
  wreduce_maxidx(mv, mi);
  if ((t & 63) == 0) { s_rv[t >> 6] = mv; s_ri[t >> 6] = mi; }
  __syncthreads();
  if (t == 0) {
    float bm = s_rv[0]; int ba = s_ri[0];
    for (int w = 1; w < 4; ++w)
      if (s_rv[w] > bm || (s_rv[w] == bm && s_ri[w] < ba)) { bm = s_rv[w]; ba = s_ri[w]; }
    s_umax = bm; s_uarg = ba;
  }
  __syncthreads();
  float se = (t < 64) ? up.s * __expf(up.m - s_umax) : 0.f;
  se = wreduce_sum(se);
  if ((t & 63) == 0) s_rs[t >> 6] = se;
  __syncthreads();
  if (t == 0) s_usum = s_rs[0] + s_rs[1] + s_rs[2] + s_rs[3];
  __syncthreads();

  // --- score parts (1024) ---
  mv = NEGV; mi = 0x7fffffff;
  for (int i = t; i < 1024; i += 256) {
    SPart p = parts[i];
    if (p.m > mv || (p.m == mv && p.a < mi)) { mv = p.m; mi = p.a; }
  }
  wreduce_maxidx(mv, mi);
  if ((t & 63) == 0) { s_rv[t >> 6] = mv; s_ri[t >> 6] = mi; }
  __syncthreads();
  if (t == 0) {
    float bm = s_rv[0]; int ba = s_ri[0];
    for (int w = 1; w < 4; ++w)
      if (s_rv[w] > bm || (s_rv[w] == bm && s_ri[w] < ba)) { bm = s_rv[w]; ba = s_ri[w]; }
    s_gm = bm; s_ga = ba;
  }
  __syncthreads();
  const float gm = s_gm;
  float ss = 0.f;
  for (int i = t; i < 1024; i += 256) {
    SPart p = parts[i];
    ss += p.s * __expf(p.m - gm);
  }
  ss = wreduce_sum(ss);
  if ((t & 63) == 0) s_rs[t >> 6] = ss;
  __syncthreads();
  if (t == 0) {
    float gsum = s_rs[0] + s_rs[1] + s_rs[2] + s_rs[3];
    float c_logp = -logf(gsum) - logf(s_usum);
    int ga = s_ga;
    if (ga == 0x7fffffff) ga = 0;
    int ci = ga >> 12, cj = ga & 4095;
    out[0] = c_logp;
    out[1] = (float)pos_idx[ci];
    out[2] = (float)neg_idx[cj];
    out[3] = (float)s_uarg;
  }
}

extern "C" void kernel_launch(void* const* d_in, const int* in_sizes, int n_in,
                              void* d_out, int out_size, void* d_ws, size_t ws_size,
                              hipStream_t stream) {
  (void)in_sizes; (void)n_in; (void)out_size; (void)ws_size;
  const float* lit    = (const float*)d_in[0];
  const float* clause = (const float*)d_in[1];
  const int* pos_idx  = (const int*)d_in[2];
  const int* neg_idx  = (const int*)d_in[3];
  const void* keep    = d_in[4];
  const void* taken   = d_in[5];
  const float* varKw  = (const float*)d_in[6];
  const float* varKb  = (const float*)d_in[7];
  const float* varQw  = (const float*)d_in[8];
  const float* varQb  = (const float*)d_in[9];
  const float* attnw  = (const float*)d_in[10];
  // d_in[11] var_attn_b: uniform shift, cancels in log_softmax max/argmax
  const float* WQw    = (const float*)d_in[12];
  const float* WQb    = (const float*)d_in[13];
  const float* WKw    = (const float*)d_in[14];
  const float* WKb    = (const float*)d_in[15];

  char* ws = (char*)d_ws;
  size_t off = 0;
  auto alloc = [&](size_t b) {
    char* p = ws + off;
    off = (off + b + 255) & ~(size_t)255;
    return p;
  };
  int* flag                  = (int*)alloc(4);
  double* qpart              = (double*)alloc((size_t)1024 * HH * 8);
  double* Qd                 = (double*)alloc(HH * 8);
  float* tvec                = (float*)alloc(HH * 4);
  float* upart               = (float*)alloc(8 * (size_t)NVARS * 4);
  unsigned long long* vmask  = (unsigned long long*)alloc((size_t)NPOS * (NMS / 64) * 8);
  float* qmat                = (float*)alloc((size_t)NPOS * HH * 4);
  float* kmat                = (float*)alloc((size_t)NMS * HH * 4);
  u16* qhi                   = (u16*)alloc((size_t)NPOS * HH * 2);
  u16* qlo                   = (u16*)alloc((size_t)NPOS * HH * 2);
  u16* khi                   = (u16*)alloc((size_t)NMS * HH * 2);
  u16* klo                   = (u16*)alloc((size_t)NMS * HH * 2);
  u16* wkhi                  = (u16*)alloc((size_t)HH * HH * 2);
  u16* wklo                  = (u16*)alloc((size_t)HH * HH * 2);
  u16* pwqhi                 = (u16*)alloc((size_t)HH * HH * 2);
  u16* pwqlo                 = (u16*)alloc((size_t)HH * HH * 2);
  u16* pwkhi                 = (u16*)alloc((size_t)HH * HH * 2);
  u16* pwklo                 = (u16*)alloc((size_t)HH * HH * 2);
  u16* lithi                 = (u16*)alloc((size_t)NVARS * HH * 2);
  u16* litlo                 = (u16*)alloc((size_t)NVARS * HH * 2);
  SPart* parts               = (SPart*)alloc(1024 * sizeof(SPart));
  SPart* uparts2             = (SPart*)alloc(64 * sizeof(SPart));

  detect_kernel<<<1, 64, 0, stream>>>((const unsigned int*)keep, flag);
  pack_kernel<<<16384, 256, 0, stream>>>(keep, taken, flag, vmask);
  qsum_kernel<<<512, 256, 0, stream>>>(clause, qpart);
  qred_kernel<<<32, 256, 0, stream>>>(qpart, Qd);
  prepmv_kernel<<<32, 256, 0, stream>>>(Qd, varQw, varQb, varKb, tvec);
  tofrag_kernel<<<128, 256, 0, stream>>>(varKw, wkhi, wklo);
  tofrag_kernel<<<128, 256, 0, stream>>>(WQw, pwqhi, pwqlo);
  tofrag_kernel<<<128, 256, 0, stream>>>(WKw, pwkhi, pwklo);
  tofrag_kernel<<<4096, 256, 0, stream>>>(lit, lithi, litlo);
  proj_kernel<<<dim3(32, 4, 2), 256, 0, stream>>>(clause, pos_idx, neg_idx,
                                                  pwqhi, pwqlo, pwkhi, pwklo,
                                                  WQb, WKb, qmat, kmat);
  tofrag_kernel<<<1024, 256, 0, stream>>>(qmat, qhi, qlo);
  tofrag_kernel<<<1024, 256, 0, stream>>>(kmat, khi, klo);
  ktu_kernel<<<dim3(128, 4), 256, 0, stream>>>(lithi, litlo, wkhi, wklo,
                                               tvec, attnw, upart);
  scores_kernel<<<1024, 256, 0, stream>>>(qhi, qlo, khi, klo, vmask, parts);
  usum_kernel<<<64, 256, 0, stream>>>(upart, uparts2);
  final_kernel<<<1, 256, 0, stream>>>(uparts2, parts, pos_idx, neg_idx,
                                      (float*)d_out);
}

// Round 7
// 222.041 us; speedup vs baseline: 2.5313x; 1.1802x over previous
//
#include <hip/hip_runtime.h>
#include <hip/hip_bf16.h>
#include <math.h>

#define HH 512
#define NVARS 16384
#define NPOS 4096
#define NMS 4096
#define NEGV -1.0e30f
#define RSQRT_H 0.04419417382415922f   // 1/sqrt(512)

#define BM 128
#define BK 16

typedef unsigned short u16;
typedef __attribute__((ext_vector_type(8))) short bf16x8;
typedef __attribute__((ext_vector_type(4))) float f32x4;

struct SPart { float m; float s; int a; int pad; };

__device__ inline u16 f2bf(float f) {
  unsigned u = __float_as_uint(f);
  unsigned r = (u + 0x7fffu + ((u >> 16) & 1u)) >> 16;
  return (u16)r;
}
__device__ inline float bf2f(u16 h) { return __uint_as_float(((unsigned)h) << 16); }

__device__ inline void wreduce_maxidx(float& v, int& idx) {
#pragma unroll
  for (int m = 1; m < 64; m <<= 1) {
    float ov = __shfl_xor(v, m, 64);
    int oi = __shfl_xor(idx, m, 64);
    if (ov > v || (ov == v && oi < idx)) { v = ov; idx = oi; }
  }
}

__device__ inline float wreduce_sum(float v) {
#pragma unroll
  for (int m = 1; m < 64; m <<= 1) v += __shfl_xor(v, m, 64);
  return v;
}

// async global->LDS: 64 lanes x 16 B; src is per-lane (already + lane*8 u16),
// dst is wave-uniform; HW writes lane i at dst + i*16 B.
__device__ __forceinline__ void stage_frag(const u16* src, u16* dst) {
  __builtin_amdgcn_global_load_lds(
      (const __attribute__((address_space(1))) void*)src,
      (__attribute__((address_space(3))) void*)dst, 16, 0, 0);
}

// ---------------------------------------------------------------------------
// Pack valid = keep & ~taken into 64-bit words; mask dtype detected inline
// (int32 masks: all words in {0,1}; byte masks: word >1 w.p. 7/8 per word).
__global__ __launch_bounds__(256) void pack_kernel(
    const void* __restrict__ keep, const void* __restrict__ taken,
    unsigned long long* __restrict__ vmask) {
  __shared__ unsigned char nib[256];
  const unsigned* kw = (const unsigned*)keep;
  int f = 1;
#pragma unroll
  for (int i = 0; i < 16; ++i) f &= (kw[i] <= 1u);
  const int t = threadIdx.x;
  const size_t e = (size_t)blockIdx.x * 1024 + (size_t)t * 4;
  int v0, v1, v2, v3;
  if (f) {
    uint4 kv = *(const uint4*)((const unsigned int*)keep + e);
    uint4 tv = *(const uint4*)((const unsigned int*)taken + e);
    v0 = kv.x && !tv.x; v1 = kv.y && !tv.y; v2 = kv.z && !tv.z; v3 = kv.w && !tv.w;
  } else {
    unsigned kv = *(const unsigned*)((const unsigned char*)keep + e);
    unsigned tv = *(const unsigned*)((const unsigned char*)taken + e);
    v0 = (kv & 0xffu) && !(tv & 0xffu);
    v1 = (kv & 0xff00u) && !(tv & 0xff00u);
    v2 = (kv & 0xff0000u) && !(tv & 0xff0000u);
    v3 = (kv & 0xff000000u) && !(tv & 0xff000000u);
  }
  nib[t] = (unsigned char)(v0 | (v1 << 1) | (v2 << 2) | (v3 << 3));
  __syncthreads();
  if (t < 16) {
    unsigned long long m = 0;
#pragma unroll
    for (int j = 0; j < 16; ++j)
      m |= (unsigned long long)nib[t * 16 + j] << (4 * j);
    vmask[(size_t)blockIdx.x * 16 + t] = m;
  }
}

// ---------------------------------------------------------------------------
// Q partial sums; float4 loads (16B/lane), 2 row-halves x 128 col-groups.
__global__ __launch_bounds__(256) void qsum_kernel(
    const float* __restrict__ clause, double* __restrict__ qpart) {
  const int b = blockIdx.x, t = threadIdx.x;
  const int fg = t & 127;
  const int rh = t >> 7;
  const float* base = clause + (size_t)(b * 128 + rh * 64) * HH + fg * 4;
  double a0 = 0.0, a1 = 0.0, a2 = 0.0, a3 = 0.0;
#pragma unroll 4
  for (int r = 0; r < 64; ++r) {
    float4 v = *(const float4*)(base + (size_t)r * HH);
    a0 += (double)v.x; a1 += (double)v.y; a2 += (double)v.z; a3 += (double)v.w;
  }
  double* o = qpart + (size_t)(b * 2 + rh) * HH + fg * 4;
  o[0] = a0; o[1] = a1; o[2] = a2; o[3] = a3;
}

// reduce 1024 partial Q vectors -> Qd[512] (f64)
__global__ __launch_bounds__(256) void qred_kernel(
    const double* __restrict__ qpart, double* __restrict__ Qd) {
  __shared__ double red[256];
  const int t = threadIdx.x;
  const int h = blockIdx.x * 16 + (t & 15);
  const int chunk = t >> 4;
  double s = 0.0;
  for (int j = 0; j < 64; ++j) s += qpart[(size_t)(chunk * 64 + j) * HH + h];
  red[t] = s;
  __syncthreads();
  for (int off = 8; off > 0; off >>= 1) {
    if (chunk < off) red[t] += red[t + off * 16];
    __syncthreads();
  }
  if (t < 16) Qd[blockIdx.x * 16 + t] = red[t];
}

// tvec[h] = (Q @ var_Q_w.T)[h] + var_Q_b[h] + var_K_b[h]
__global__ __launch_bounds__(256) void prepmv_kernel(
    const double* __restrict__ Qd, const float* __restrict__ varQw,
    const float* __restrict__ varQb, const float* __restrict__ varKb,
    float* __restrict__ tvec) {
  __shared__ double red[256];
  const int t = threadIdx.x;
  const int h = blockIdx.x * 16 + (t & 15);
  const int chunk = t >> 4;
  const float* wrow = varQw + (size_t)h * HH + chunk * 32;
  const double* qd = Qd + chunk * 32;
  double s = 0.0;
  for (int j = 0; j < 32; ++j) s += qd[j] * (double)wrow[j];
  red[t] = s;
  __syncthreads();
  for (int off = 8; off > 0; off >>= 1) {
    if (chunk < off) red[t] += red[t + off * 16];
    __syncthreads();
  }
  if (t < 16) {
    int hh = blockIdx.x * 16 + t;
    tvec[hh] = (float)(red[t] + (double)varQb[hh] + (double)varKb[hh]);
  }
}

// ---------------------------------------------------------------------------
// convert a row-major f32 matrix [nrow x 512] into fragment-major bf16 hi/lo.
// frag f: rows (f>>4)*16..+16, cols (f&15)*32..+32; lane l holds row (l&15),
// k-chunk (l>>4)*8. flat addr = f*512 + lane*8.
__global__ __launch_bounds__(256) void tofrag_kernel(
    const float* __restrict__ src, u16* __restrict__ hi, u16* __restrict__ lo) {
  const int frag = blockIdx.x * 4 + (threadIdx.x >> 6);
  const int lane = threadIdx.x & 63;
  const int R = frag >> 4, K = frag & 15;
  const float* p = src + (size_t)(R * 16 + (lane & 15)) * HH + K * 32 + (lane >> 4) * 8;
  float v[8];
  *(float4*)&v[0] = *(const float4*)p;
  *(float4*)&v[4] = *(const float4*)(p + 4);
  u16 h[8], l[8];
#pragma unroll
  for (int e = 0; e < 8; ++e) { h[e] = f2bf(v[e]); l[e] = f2bf(v[e] - bf2f(h[e])); }
  size_t base = (size_t)frag * 512 + (size_t)lane * 8;
  *(ushort4*)(hi + base) = *(ushort4*)&h[0];
  *(ushort4*)(hi + base + 4) = *(ushort4*)&h[4];
  *(ushort4*)(lo + base) = *(ushort4*)&l[0];
  *(ushort4*)(lo + base + 4) = *(ushort4*)&l[4];
}

// ---------------------------------------------------------------------------
// MFMA macros: pass-outer interleave; pass order hh, hl, lh preserved.
#define MFMA16(A, B)                                                                 \
  _Pragma("unroll") for (int i_ = 0; i_ < 4; ++i_)                                   \
  _Pragma("unroll") for (int j_ = 0; j_ < 4; ++j_)                                   \
    acc[i_][j_] = __builtin_amdgcn_mfma_f32_16x16x32_bf16(A[i_], B[j_], acc[i_][j_], 0, 0, 0);

#define MFMAS(AH, AL, BH, BL)                                                        \
  do { MFMA16(AH, BH) MFMA16(AH, BL) MFMA16(AL, BH) } while (0)

// ---------------------------------------------------------------------------
// q/k projection as 3-pass split-bf16 MFMA with on-the-fly A gather+split.
// Writes row-major f32 (split to fragments by tofrag afterwards).
__global__ __launch_bounds__(256, 3) void proj_kernel(
    const float* __restrict__ clause,
    const int* __restrict__ pos_idx, const int* __restrict__ neg_idx,
    const u16* __restrict__ wqhi, const u16* __restrict__ wqlo,
    const u16* __restrict__ wkhi2, const u16* __restrict__ wklo2,
    const float* __restrict__ bQ, const float* __restrict__ bK,
    float* __restrict__ qmat, float* __restrict__ kmat) {
  const int* __restrict__ idx = blockIdx.z ? neg_idx : pos_idx;
  const u16* __restrict__ bhp = blockIdx.z ? wkhi2 : wqhi;
  const u16* __restrict__ blp = blockIdx.z ? wklo2 : wqlo;
  const float* __restrict__ bias = blockIdx.z ? bK : bQ;
  float* __restrict__ out = blockIdx.z ? kmat : qmat;

  const int t = threadIdx.x, lane = t & 63, wid = t >> 6;
  const int wn = wid & 1, wm = wid >> 1;
  const int row0 = blockIdx.x * 128;
  const int col0 = blockIdx.y * 128;

  const float* aptr[4];
#pragma unroll
  for (int f = 0; f < 4; ++f) {
    int g = idx[row0 + wn * 64 + f * 16 + (lane & 15)];
    aptr[f] = clause + (size_t)g * HH + (lane >> 4) * 8;
  }
  const size_t bbase = (size_t)((col0 >> 4) + wm * 4) * 8192 + (size_t)lane * 8;

  f32x4 acc[4][4] = {};
#pragma unroll
  for (int s = 0; s < 16; ++s) {
    float rA[4][8];
    bf16x8 aH[4], aL[4], bH[4], bL[4];
#pragma unroll
    for (int f = 0; f < 4; ++f) {
      *(float4*)&rA[f][0] = *(const float4*)(aptr[f] + s * 32);
      *(float4*)&rA[f][4] = *(const float4*)(aptr[f] + s * 32 + 4);
      size_t ob = bbase + (size_t)f * 8192 + (size_t)s * 512;
      bH[f] = *(const bf16x8*)(bhp + ob);
      bL[f] = *(const bf16x8*)(blp + ob);
    }
#pragma unroll
    for (int f = 0; f < 4; ++f)
#pragma unroll
      for (int e = 0; e < 8; ++e) {
        float v = rA[f][e];
        u16 h = f2bf(v);
        aH[f][e] = (short)h;
        aL[f][e] = (short)f2bf(v - bf2f(h));
      }
    MFMAS(aH, aL, bH, bL);
  }

#pragma unroll
  for (int i = 0; i < 4; ++i)
#pragma unroll
    for (int j = 0; j < 4; ++j) {
      int h = col0 + wm * 64 + j * 16 + (lane & 15);
      float b = bias[h];
#pragma unroll
      for (int r = 0; r < 4; ++r) {
        int n = row0 + wn * 64 + i * 16 + (lane >> 4) * 4 + r;
        out[(size_t)n * HH + h] = acc[i][j][r] + b;
      }
    }
}

// ---------------------------------------------------------------------------
// LDS-staged 3-pass split GEMM stage macro pieces shared by ktu/scores.
// lds[buf][region][frag][512]: region 0=A-hi 1=A-lo 2=B-hi 3=B-lo; each wave
// stages its own region (8 x global_load_lds width-16, linear dest).

// K_t GEMM (lit @ varKw.T) via LDS-staged MFMA; tanh epilogue.
__global__ __launch_bounds__(256, 2) void ktu_kernel(
    const u16* __restrict__ lithi, const u16* __restrict__ litlo,
    const u16* __restrict__ wkhi, const u16* __restrict__ wklo,
    const float* __restrict__ tvec, const float* __restrict__ attnw,
    float* __restrict__ upart) {
  __shared__ __align__(16) u16 lds[2][4][8][512];
  const int t = threadIdx.x, lane = t & 63, wid = t >> 6;
  const int wn = wid & 1, wm = wid >> 1;
  const int row0 = blockIdx.x * 128;
  const int l8 = lane * 8;

  const u16* sa = (wid == 0) ? lithi : (wid == 1) ? litlo : (wid == 2) ? wkhi : wklo;
  const int rb = (wid < 2) ? (row0 >> 4) : (blockIdx.y * 8);
  const u16* sab = sa + (size_t)rb * 8192 + l8;

#define KSTAGE(buf, s)                                                        \
  _Pragma("unroll") for (int f_ = 0; f_ < 8; ++f_)                            \
    stage_frag(sab + (size_t)f_ * 8192 + (size_t)(s) * 512,                   \
               &lds[buf][wid][f_][0]);

  KSTAGE(0, 0)
  f32x4 acc[4][4] = {};
#pragma unroll
  for (int s = 0; s < 16; ++s) {
    __syncthreads();                       // drain: buf[s&1] staged & prev reads done
    if (s < 15) { KSTAGE((s + 1) & 1, s + 1) }
    const int b = s & 1;
    bf16x8 aH[4], aL[4], bH[4], bL[4];
#pragma unroll
    for (int f = 0; f < 4; ++f) {
      aH[f] = *(const bf16x8*)&lds[b][0][wn * 4 + f][l8];
      aL[f] = *(const bf16x8*)&lds[b][1][wn * 4 + f][l8];
      bH[f] = *(const bf16x8*)&lds[b][2][wm * 4 + f][l8];
      bL[f] = *(const bf16x8*)&lds[b][3][wm * 4 + f][l8];
    }
    MFMAS(aH, aL, bH, bL);
  }
#undef KSTAGE

  // epilogue: u partial = sum_c tanh(K_t + tvec[c]) * attnw[c]
  const int cbase = blockIdx.y * 128 + wm * 64;
  float tv[4], aw[4];
#pragma unroll
  for (int j = 0; j < 4; ++j) {
    int c = cbase + j * 16 + (lane & 15);
    tv[j] = tvec[c]; aw[j] = attnw[c];
  }
  float us[4][4];
#pragma unroll
  for (int i = 0; i < 4; ++i)
#pragma unroll
    for (int r = 0; r < 4; ++r) {
      float s = 0.f;
#pragma unroll
      for (int j = 0; j < 4; ++j) {
        float x = acc[i][j][r] + tv[j];
        float th = 1.0f - 2.0f / (__expf(2.0f * x) + 1.0f);   // safe tanh
        s += th * aw[j];
      }
      us[i][r] = s;
    }
#pragma unroll
  for (int m = 1; m < 16; m <<= 1)
#pragma unroll
    for (int i = 0; i < 4; ++i)
#pragma unroll
      for (int r = 0; r < 4; ++r) us[i][r] += __shfl_xor(us[i][r], m, 64);
  if ((lane & 15) == 0) {
#pragma unroll
    for (int i = 0; i < 4; ++i)
#pragma unroll
      for (int r = 0; r < 4; ++r) {
        int row = row0 + wn * 64 + i * 16 + (lane >> 4) * 4 + r;
        upart[(size_t)(blockIdx.y * 2 + wm) * NVARS + row] = us[i][r];
      }
  }
}

// ---------------------------------------------------------------------------
// scores = q @ k.T / sqrt(H): LDS-staged 3-pass split MFMA + XCD supertile
// swizzle; masked max/argmax/sumexp epilogue.
__global__ __launch_bounds__(256, 2) void scores_kernel(
    const u16* __restrict__ qhi, const u16* __restrict__ qlo,
    const u16* __restrict__ khi, const u16* __restrict__ klo,
    const unsigned long long* __restrict__ vmask, SPart* __restrict__ parts) {
  __shared__ __align__(16) u16 lds[2][4][8][512];
  __shared__ unsigned long long mrow[128][2];
  __shared__ float s_rv[4]; __shared__ int s_ri[4]; __shared__ float s_rs[4];
  __shared__ float s_bm; __shared__ int s_ba;

  const int t = threadIdx.x;
  const int lane = t & 63;
  const int wid = t >> 6;
  const int wn = wid & 1, wm = wid >> 1;
  const int l8 = lane * 8;

  // XCD supertile swizzle (bijective on [0,1024))
  const int bid = blockIdx.x;
  const int xcd = bid & 7, p = bid >> 3;
  const int sp = p >> 6, q = p & 63;
  const int g = xcd * 2 + sp;
  const int bx = (g & 3) * 8 + (q & 7);
  const int by = (g >> 2) * 8 + (q >> 3);

  const int n0 = by * 128;
  const int m0 = bx * 128;

  const u16* sa = (wid == 0) ? qhi : (wid == 1) ? qlo : (wid == 2) ? khi : klo;
  const int rb = (wid < 2) ? (n0 >> 4) : (m0 >> 4);
  const u16* sab = sa + (size_t)rb * 8192 + l8;

#define SSTAGE(buf, s)                                                        \
  _Pragma("unroll") for (int f_ = 0; f_ < 8; ++f_)                            \
    stage_frag(sab + (size_t)f_ * 8192 + (size_t)(s) * 512,                   \
               &lds[buf][wid][f_][0]);

  // stage masks (synced by first loop barrier)
  {
    int r = t >> 1, w = t & 1;
    mrow[r][w] = vmask[(size_t)(n0 + r) * (NMS / 64) + (m0 >> 6) + w];
  }

  SSTAGE(0, 0)
  f32x4 acc[4][4] = {};
#pragma unroll
  for (int s = 0; s < 16; ++s) {
    __syncthreads();
    if (s < 15) { SSTAGE((s + 1) & 1, s + 1) }
    const int b = s & 1;
    bf16x8 aH[4], aL[4], bH[4], bL[4];
#pragma unroll
    for (int f = 0; f < 4; ++f) {
      aH[f] = *(const bf16x8*)&lds[b][0][wn * 4 + f][l8];
      aL[f] = *(const bf16x8*)&lds[b][1][wn * 4 + f][l8];
      bH[f] = *(const bf16x8*)&lds[b][2][wm * 4 + f][l8];
      bL[f] = *(const bf16x8*)&lds[b][3][wm * 4 + f][l8];
    }
    MFMAS(aH, aL, bH, bL);
  }
#undef SSTAGE

  // C/D layout: col = lane&15, row = (lane>>4)*4 + reg
  const int rbase = wn * 64 + (lane >> 4) * 4;
  const int cb15 = (lane & 15);

  float mv = NEGV; int mi = 0x7fffffff;
#pragma unroll
  for (int i = 0; i < 4; ++i) {
#pragma unroll
    for (int r = 0; r < 4; ++r) {
      int rl = rbase + i * 16 + r;
      unsigned long long ww = mrow[rl][wm];
      int gb = (n0 + rl) * NMS + m0;
#pragma unroll
      for (int j = 0; j < 4; ++j) {
        int bit = j * 16 + cb15;
        int cl = wm * 64 + bit;
        float sv = acc[i][j][r] * RSQRT_H;
        acc[i][j][r] = sv;
        bool valid = ((ww >> bit) & 1ull) != 0;
        if (valid && (sv > mv || (sv == mv && gb + cl < mi))) { mv = sv; mi = gb + cl; }
      }
    }
  }
  wreduce_maxidx(mv, mi);
  if ((t & 63) == 0) { s_rv[wid] = mv; s_ri[wid] = mi; }
  __syncthreads();
  if (t == 0) {
    float bm = s_rv[0]; int ba = s_ri[0];
    for (int w = 1; w < 4; ++w)
      if (s_rv[w] > bm || (s_rv[w] == bm && s_ri[w] < ba)) { bm = s_rv[w]; ba = s_ri[w]; }
    s_bm = bm; s_ba = ba;
  }
  __syncthreads();
  const float bm = s_bm;

  float se = 0.f;
#pragma unroll
  for (int i = 0; i < 4; ++i) {
#pragma unroll
    for (int r = 0; r < 4; ++r) {
      int rl = rbase + i * 16 + r;
      unsigned long long ww = mrow[rl][wm];
#pragma unroll
      for (int j = 0; j < 4; ++j) {
        int bit = j * 16 + cb15;
        bool valid = ((ww >> bit) & 1ull) != 0;
        if (valid) se += __expf(acc[i][j][r] - bm);
      }
    }
  }
  se = wreduce_sum(se);
  if ((t & 63) == 0) s_rs[wid] = se;
  __syncthreads();
  if (t == 0) {
    SPart pt;
    pt.m = s_bm;
    pt.s = s_rs[0] + s_rs[1] + s_rs[2] + s_rs[3];
    pt.a = s_ba; pt.pad = 0;
    parts[by * 32 + bx] = pt;
  }
}

// ---------------------------------------------------------------------------
// u reduction stage 1: 64 blocks x 256 vars -> per-block {max, argmax, sumexp}.
__global__ __launch_bounds__(256) void usum_kernel(
    const float* __restrict__ upart, SPart* __restrict__ uparts2) {
  __shared__ float s_rv[4]; __shared__ int s_ri[4]; __shared__ float s_rs[4];
  __shared__ float s_bm; __shared__ int s_ba;
  const int t = threadIdx.x;
  const int i = blockIdx.x * 256 + t;
  float u = 0.f;
#pragma unroll
  for (int p = 0; p < 8; ++p) u += upart[(size_t)p * NVARS + i];
  float mv = u; int mi = i;
  wreduce_maxidx(mv, mi);
  if ((t & 63) == 0) { s_rv[t >> 6] = mv; s_ri[t >> 6] = mi; }
  __syncthreads();
  if (t == 0) {
    float bm = s_rv[0]; int ba = s_ri[0];
    for (int w = 1; w < 4; ++w)
      if (s_rv[w] > bm || (s_rv[w] == bm && s_ri[w] < ba)) { bm = s_rv[w]; ba = s_ri[w]; }
    s_bm = bm; s_ba = ba;
  }
  __syncthreads();
  float se = __expf(u - s_bm);
  se = wreduce_sum(se);
  if ((t & 63) == 0) s_rs[t >> 6] = se;
  __syncthreads();
  if (t == 0) {
    SPart p;
    p.m = s_bm;
    p.s = s_rs[0] + s_rs[1] + s_rs[2] + s_rs[3];
    p.a = s_ba; p.pad = 0;
    uparts2[blockIdx.x] = p;
  }
}

// ---------------------------------------------------------------------------
// Final combine.  d_out is FLOAT32 x4: {c_logp, pos_idx[ci], neg_idx[cj], var_idx}.
__global__ __launch_bounds__(256) void final_kernel(
    const SPart* __restrict__ uparts2, const SPart* __restrict__ parts,
    const int* __restrict__ pos_idx, const int* __restrict__ neg_idx,
    float* __restrict__ out) {
  __shared__ float s_rv[4]; __shared__ int s_ri[4]; __shared__ float s_rs[4];
  __shared__ float s_umax; __shared__ int s_uarg; __shared__ float s_usum;
  __shared__ float s_gm; __shared__ int s_ga;
  const int t = threadIdx.x;

  // --- u parts (64) ---
  float mv = -3.0e38f; int mi = 0x7fffffff;
  SPart up;
  if (t < 64) {
    up = uparts2[t];
    mv = up.m; mi = up.a;
  }
  wreduce_maxidx(mv, mi);
  if ((t & 63) == 0) { s_rv[t >> 6] = mv; s_ri[t >> 6] = mi; }
  __syncthreads();
  if (t == 0) {
    float bm = s_rv[0]; int ba = s_ri[0];
    for (int w = 1; w < 4; ++w)
      if (s_rv[w] > bm || (s_rv[w] == bm && s_ri[w] < ba)) { bm = s_rv[w]; ba = s_ri[w]; }
    s_umax = bm; s_uarg = ba;
  }
  __syncthreads();
  float se = (t < 64) ? up.s * __expf(up.m - s_umax) : 0.f;
  se = wreduce_sum(se);
  if ((t & 63) == 0) s_rs[t >> 6] = se;
  __syncthreads();
  if (t == 0) s_usum = s_rs[0] + s_rs[1] + s_rs[2] + s_rs[3];
  __syncthreads();

  // --- score parts (1024) ---
  mv = NEGV; mi = 0x7fffffff;
  for (int i = t; i < 1024; i += 256) {
    SPart p = parts[i];
    if (p.m > mv || (p.m == mv && p.a < mi)) { mv = p.m; mi = p.a; }
  }
  wreduce_maxidx(mv, mi);
  if ((t & 63) == 0) { s_rv[t >> 6] = mv; s_ri[t >> 6] = mi; }
  __syncthreads();
  if (t == 0) {
    float bm = s_rv[0]; int ba = s_ri[0];
    for (int w = 1; w < 4; ++w)
      if (s_rv[w] > bm || (s_rv[w] == bm && s_ri[w] < ba)) { bm = s_rv[w]; ba = s_ri[w]; }
    s_gm = bm; s_ga = ba;
  }
  __syncthreads();
  const float gm = s_gm;
  float ss = 0.f;
  for (int i = t; i < 1024; i += 256) {
    SPart p = parts[i];
    ss += p.s * __expf(p.m - gm);
  }
  ss = wreduce_sum(ss);
  if ((t & 63) == 0) s_rs[t >> 6] = ss;
  __syncthreads();
  if (t == 0) {
    float gsum = s_rs[0] + s_rs[1] + s_rs[2] + s_rs[3];
    float c_logp = -logf(gsum) - logf(s_usum);
    int ga = s_ga;
    if (ga == 0x7fffffff) ga = 0;
    int ci = ga >> 12, cj = ga & 4095;
    out[0] = c_logp;
    out[1] = (float)pos_idx[ci];
    out[2] = (float)neg_idx[cj];
    out[3] = (float)s_uarg;
  }
}

extern "C" void kernel_launch(void* const* d_in, const int* in_sizes, int n_in,
                              void* d_out, int out_size, void* d_ws, size_t ws_size,
                              hipStream_t stream) {
  (void)in_sizes; (void)n_in; (void)out_size; (void)ws_size;
  const float* lit    = (const float*)d_in[0];
  const float* clause = (const float*)d_in[1];
  const int* pos_idx  = (const int*)d_in[2];
  const int* neg_idx  = (const int*)d_in[3];
  const void* keep    = d_in[4];
  const void* taken   = d_in[5];
  const float* varKw  = (const float*)d_in[6];
  const float* varKb  = (const float*)d_in[7];
  const float* varQw  = (const float*)d_in[8];
  const float* varQb  = (const float*)d_in[9];
  const float* attnw  = (const float*)d_in[10];
  // d_in[11] var_attn_b: uniform shift, cancels in log_softmax max/argmax
  const float* WQw    = (const float*)d_in[12];
  const float* WQb    = (const float*)d_in[13];
  const float* WKw    = (const float*)d_in[14];
  const float* WKb    = (const float*)d_in[15];

  char* ws = (char*)d_ws;
  size_t off = 0;
  auto alloc = [&](size_t b) {
    char* p = ws + off;
    off = (off + b + 255) & ~(size_t)255;
    return p;
  };
  double* qpart              = (double*)alloc((size_t)1024 * HH * 8);
  double* Qd                 = (double*)alloc(HH * 8);
  float* tvec                = (float*)alloc(HH * 4);
  float* upart               = (float*)alloc(8 * (size_t)NVARS * 4);
  unsigned long long* vmask  = (unsigned long long*)alloc((size_t)NPOS * (NMS / 64) * 8);
  float* qmat                = (float*)alloc((size_t)NPOS * HH * 4);
  float* kmat                = (float*)alloc((size_t)NMS * HH * 4);
  u16* qhi                   = (u16*)alloc((size_t)NPOS * HH * 2);
  u16* qlo                   = (u16*)alloc((size_t)NPOS * HH * 2);
  u16* khi                   = (u16*)alloc((size_t)NMS * HH * 2);
  u16* klo                   = (u16*)alloc((size_t)NMS * HH * 2);
  u16* wkhi                  = (u16*)alloc((size_t)HH * HH * 2);
  u16* wklo                  = (u16*)alloc((size_t)HH * HH * 2);
  u16* pwqhi                 = (u16*)alloc((size_t)HH * HH * 2);
  u16* pwqlo                 = (u16*)alloc((size_t)HH * HH * 2);
  u16* pwkhi                 = (u16*)alloc((size_t)HH * HH * 2);
  u16* pwklo                 = (u16*)alloc((size_t)HH * HH * 2);
  u16* lithi                 = (u16*)alloc((size_t)NVARS * HH * 2);
  u16* litlo                 = (u16*)alloc((size_t)NVARS * HH * 2);
  SPart* parts               = (SPart*)alloc(1024 * sizeof(SPart));
  SPart* uparts2             = (SPart*)alloc(64 * sizeof(SPart));

  pack_kernel<<<16384, 256, 0, stream>>>(keep, taken, vmask);
  qsum_kernel<<<512, 256, 0, stream>>>(clause, qpart);
  qred_kernel<<<32, 256, 0, stream>>>(qpart, Qd);
  prepmv_kernel<<<32, 256, 0, stream>>>(Qd, varQw, varQb, varKb, tvec);
  tofrag_kernel<<<128, 256, 0, stream>>>(varKw, wkhi, wklo);
  tofrag_kernel<<<128, 256, 0, stream>>>(WQw, pwqhi, pwqlo);
  tofrag_kernel<<<128, 256, 0, stream>>>(WKw, pwkhi, pwklo);
  tofrag_kernel<<<4096, 256, 0, stream>>>(lit, lithi, litlo);
  proj_kernel<<<dim3(32, 4, 2), 256, 0, stream>>>(clause, pos_idx, neg_idx,
                                                  pwqhi, pwqlo, pwkhi, pwklo,
                                                  WQb, WKb, qmat, kmat);
  tofrag_kernel<<<1024, 256, 0, stream>>>(qmat, qhi, qlo);
  tofrag_kernel<<<1024, 256, 0, stream>>>(kmat, khi, klo);
  ktu_kernel<<<dim3(128, 4), 256, 0, stream>>>(lithi, litlo, wkhi, wklo,
                                               tvec, attnw, upart);
  scores_kernel<<<1024, 256, 0, stream>>>(qhi, qlo, khi, klo, vmask, parts);
  usum_kernel<<<64, 256, 0, stream>>>(upart, uparts2);
  final_kernel<<<1, 256, 0, stream>>>(uparts2, parts, pos_idx, neg_idx,
                                      (float*)d_out);
}

// Round 8
// 217.439 us; speedup vs baseline: 2.5849x; 1.0212x over previous
//
#include <hip/hip_runtime.h>
#include <hip/hip_bf16.h>
#include <math.h>

#define HH 512
#define NVARS 16384
#define NPOS 4096
#define NMS 4096
#define NEGV -1.0e30f
#define RSQRT_H 0.04419417382415922f   // 1/sqrt(512)

typedef unsigned short u16;
typedef __attribute__((ext_vector_type(8))) short bf16x8;
typedef __attribute__((ext_vector_type(4))) float f32x4;

struct SPart { float m; float s; int a; int pad; };

__device__ inline u16 f2bf(float f) {
  unsigned u = __float_as_uint(f);
  unsigned r = (u + 0x7fffu + ((u >> 16) & 1u)) >> 16;
  return (u16)r;
}
__device__ inline float bf2f(u16 h) { return __uint_as_float(((unsigned)h) << 16); }

__device__ inline void wreduce_maxidx(float& v, int& idx) {
#pragma unroll
  for (int m = 1; m < 64; m <<= 1) {
    float ov = __shfl_xor(v, m, 64);
    int oi = __shfl_xor(idx, m, 64);
    if (ov > v || (ov == v && oi < idx)) { v = ov; idx = oi; }
  }
}

__device__ inline float wreduce_sum(float v) {
#pragma unroll
  for (int m = 1; m < 64; m <<= 1) v += __shfl_xor(v, m, 64);
  return v;
}

// async global->LDS: 64 lanes x 16 B; src per-lane (already + lane*8 u16),
// dst wave-uniform; HW writes lane i at dst + i*16 B.
__device__ __forceinline__ void stage_frag(const u16* src, u16* dst) {
  __builtin_amdgcn_global_load_lds(
      (const __attribute__((address_space(1))) void*)src,
      (__attribute__((address_space(3))) void*)dst, 16, 0, 0);
}

// row-major f32 [.. x 512] -> fragment-major bf16 hi/lo for one frag.
// frag f: rows (f>>4)*16..+16, cols (f&15)*32..+32; lane l: row l&15,
// k-chunk (l>>4)*8; flat = f*512 + l*8.
__device__ __forceinline__ void do_tofrag(
    const float* __restrict__ src, u16* __restrict__ hi, u16* __restrict__ lo,
    int frag, int lane) {
  const int R = frag >> 4, K = frag & 15;
  const float* p = src + (size_t)(R * 16 + (lane & 15)) * HH + K * 32 + (lane >> 4) * 8;
  float v[8];
  *(float4*)&v[0] = *(const float4*)p;
  *(float4*)&v[4] = *(const float4*)(p + 4);
  u16 h[8], l[8];
#pragma unroll
  for (int e = 0; e < 8; ++e) { h[e] = f2bf(v[e]); l[e] = f2bf(v[e] - bf2f(h[e])); }
  size_t base = (size_t)frag * 512 + (size_t)lane * 8;
  *(ushort4*)(hi + base) = *(ushort4*)&h[0];
  *(ushort4*)(hi + base + 4) = *(ushort4*)&h[4];
  *(ushort4*)(lo + base) = *(ushort4*)&l[0];
  *(ushort4*)(lo + base + 4) = *(ushort4*)&l[4];
}

// ---------------------------------------------------------------------------
// Fused BW-bound preamble: pack masks + qsum partials + lit tofrag + weight
// tofrags, branched on blockIdx.x (wave-uniform per block).
//   [0, 16384)        : pack
//   [16384, 16896)    : qsum (512 blocks)
//   [16896, 20992)    : lit tofrag (4096 blocks)
//   [20992, 21376)    : weight tofrag (3 x 128 blocks)
__global__ __launch_bounds__(256) void prep_kernel(
    const void* __restrict__ keep, const void* __restrict__ taken,
    unsigned long long* __restrict__ vmask,
    const float* __restrict__ clause, double* __restrict__ qpart,
    const float* __restrict__ lit, u16* __restrict__ lithi, u16* __restrict__ litlo,
    const float* __restrict__ varKw, u16* __restrict__ wkhi, u16* __restrict__ wklo,
    const float* __restrict__ WQw, u16* __restrict__ pwqhi, u16* __restrict__ pwqlo,
    const float* __restrict__ WKw, u16* __restrict__ pwkhi, u16* __restrict__ pwklo) {
  const int bid = blockIdx.x;
  const int t = threadIdx.x;
  if (bid < 16384) {
    // ---- pack: valid = keep & ~taken -> bitmask (dtype detected inline) ----
    __shared__ unsigned char nib[256];
    const unsigned* kw = (const unsigned*)keep;
    int f = 1;
#pragma unroll
    for (int i = 0; i < 16; ++i) f &= (kw[i] <= 1u);
    const size_t e = (size_t)bid * 1024 + (size_t)t * 4;
    int v0, v1, v2, v3;
    if (f) {
      uint4 kv = *(const uint4*)((const unsigned int*)keep + e);
      uint4 tv = *(const uint4*)((const unsigned int*)taken + e);
      v0 = kv.x && !tv.x; v1 = kv.y && !tv.y; v2 = kv.z && !tv.z; v3 = kv.w && !tv.w;
    } else {
      unsigned kv = *(const unsigned*)((const unsigned char*)keep + e);
      unsigned tv = *(const unsigned*)((const unsigned char*)taken + e);
      v0 = (kv & 0xffu) && !(tv & 0xffu);
      v1 = (kv & 0xff00u) && !(tv & 0xff00u);
      v2 = (kv & 0xff0000u) && !(tv & 0xff0000u);
      v3 = (kv & 0xff000000u) && !(tv & 0xff000000u);
    }
    nib[t] = (unsigned char)(v0 | (v1 << 1) | (v2 << 2) | (v3 << 3));
    __syncthreads();
    if (t < 16) {
      unsigned long long m = 0;
#pragma unroll
      for (int j = 0; j < 16; ++j)
        m |= (unsigned long long)nib[t * 16 + j] << (4 * j);
      vmask[(size_t)bid * 16 + t] = m;
    }
  } else if (bid < 16896) {
    // ---- qsum: f64 partial column sums of clause ----
    const int b = bid - 16384;
    const int fg = t & 127;
    const int rh = t >> 7;
    const float* base = clause + (size_t)(b * 128 + rh * 64) * HH + fg * 4;
    double a0 = 0.0, a1 = 0.0, a2 = 0.0, a3 = 0.0;
#pragma unroll 4
    for (int r = 0; r < 64; ++r) {
      float4 v = *(const float4*)(base + (size_t)r * HH);
      a0 += (double)v.x; a1 += (double)v.y; a2 += (double)v.z; a3 += (double)v.w;
    }
    double* o = qpart + (size_t)(b * 2 + rh) * HH + fg * 4;
    o[0] = a0; o[1] = a1; o[2] = a2; o[3] = a3;
  } else if (bid < 20992) {
    // ---- lit tofrag ----
    const int frag = (bid - 16896) * 4 + (t >> 6);
    do_tofrag(lit, lithi, litlo, frag, t & 63);
  } else {
    // ---- weight tofrags ----
    const int wb = bid - 20992;
    const int m = wb >> 7;
    const int frag = (wb & 127) * 4 + (t >> 6);
    const float* src = (m == 0) ? varKw : (m == 1) ? WQw : WKw;
    u16* hi = (m == 0) ? wkhi : (m == 1) ? pwqhi : pwkhi;
    u16* lo = (m == 0) ? wklo : (m == 1) ? pwqlo : pwklo;
    do_tofrag(src, hi, lo, frag, t & 63);
  }
}

// reduce 1024 partial Q vectors -> Qd[512] (f64)
__global__ __launch_bounds__(256) void qred_kernel(
    const double* __restrict__ qpart, double* __restrict__ Qd) {
  __shared__ double red[256];
  const int t = threadIdx.x;
  const int h = blockIdx.x * 16 + (t & 15);
  const int chunk = t >> 4;
  double s = 0.0;
  for (int j = 0; j < 64; ++j) s += qpart[(size_t)(chunk * 64 + j) * HH + h];
  red[t] = s;
  __syncthreads();
  for (int off = 8; off > 0; off >>= 1) {
    if (chunk < off) red[t] += red[t + off * 16];
    __syncthreads();
  }
  if (t < 16) Qd[blockIdx.x * 16 + t] = red[t];
}

// tvec[h] = (Q @ var_Q_w.T)[h] + var_Q_b[h] + var_K_b[h]
__global__ __launch_bounds__(256) void prepmv_kernel(
    const double* __restrict__ Qd, const float* __restrict__ varQw,
    const float* __restrict__ varQb, const float* __restrict__ varKb,
    float* __restrict__ tvec) {
  __shared__ double red[256];
  const int t = threadIdx.x;
  const int h = blockIdx.x * 16 + (t & 15);
  const int chunk = t >> 4;
  const float* wrow = varQw + (size_t)h * HH + chunk * 32;
  const double* qd = Qd + chunk * 32;
  double s = 0.0;
  for (int j = 0; j < 32; ++j) s += qd[j] * (double)wrow[j];
  red[t] = s;
  __syncthreads();
  for (int off = 8; off > 0; off >>= 1) {
    if (chunk < off) red[t] += red[t + off * 16];
    __syncthreads();
  }
  if (t < 16) {
    int hh = blockIdx.x * 16 + t;
    tvec[hh] = (float)(red[t] + (double)varQb[hh] + (double)varKb[hh]);
  }
}

// ---------------------------------------------------------------------------
// MFMA macros: pass-outer interleave; pass order hh, hl, lh preserved.
#define MFMA16(A, B)                                                                 \
  _Pragma("unroll") for (int i_ = 0; i_ < 4; ++i_)                                   \
  _Pragma("unroll") for (int j_ = 0; j_ < 4; ++j_)                                   \
    acc[i_][j_] = __builtin_amdgcn_mfma_f32_16x16x32_bf16(A[i_], B[j_], acc[i_][j_], 0, 0, 0);

#define MFMAS(AH, AL, BH, BL)                                                        \
  do { MFMA16(AH, BH) MFMA16(AH, BL) MFMA16(AL, BH) } while (0)

// ---------------------------------------------------------------------------
// q/k projection: A = W fragments (pre-split), B = gathered clause rows
// (on-the-fly split).  C layout then has lane&15 = n (output row) and
// (lane>>4)*4+reg = h (output col) -> 4 consecutive h per lane = one ushort4
// fragment write for hi and lo (no f32 round-trip, no tofrag pass).
// Pass order MFMA(AH,BH); MFMA(AL,BH); MFMA(AH,BL) reproduces the old
// (ChWh, ChWl, ClWh) accumulation order bit-exactly.
__global__ __launch_bounds__(256, 3) void proj_kernel(
    const float* __restrict__ clause,
    const int* __restrict__ pos_idx, const int* __restrict__ neg_idx,
    const u16* __restrict__ pwqhi, const u16* __restrict__ pwqlo,
    const u16* __restrict__ pwkhi, const u16* __restrict__ pwklo,
    const float* __restrict__ bQ, const float* __restrict__ bK,
    u16* __restrict__ qhi, u16* __restrict__ qlo,
    u16* __restrict__ khi, u16* __restrict__ klo) {
  const int* __restrict__ idx = blockIdx.z ? neg_idx : pos_idx;
  const u16* __restrict__ whp = blockIdx.z ? pwkhi : pwqhi;
  const u16* __restrict__ wlp = blockIdx.z ? pwklo : pwqlo;
  const float* __restrict__ bias = blockIdx.z ? bK : bQ;
  u16* __restrict__ ohi = blockIdx.z ? khi : qhi;
  u16* __restrict__ olo = blockIdx.z ? klo : qlo;

  const int t = threadIdx.x, lane = t & 63, wid = t >> 6;
  const int wn = wid & 1, wm = wid >> 1;
  const int row0 = blockIdx.x * 128;   // output rows (n)
  const int col0 = blockIdx.y * 128;   // output cols (h)

  // B operand: gathered clause rows
  const float* bptr[4];
#pragma unroll
  for (int j = 0; j < 4; ++j) {
    int g = idx[row0 + wn * 64 + j * 16 + (lane & 15)];
    bptr[j] = clause + (size_t)g * HH + (lane >> 4) * 8;
  }
  // A operand: W fragments for h-tiles
  const size_t abase = (size_t)((col0 >> 4) + wm * 4) * 8192 + (size_t)lane * 8;

  f32x4 acc[4][4] = {};
#pragma unroll
  for (int s = 0; s < 16; ++s) {
    float rB[4][8];
    bf16x8 aH[4], aL[4], bH[4], bL[4];
#pragma unroll
    for (int f = 0; f < 4; ++f) {
      *(float4*)&rB[f][0] = *(const float4*)(bptr[f] + s * 32);
      *(float4*)&rB[f][4] = *(const float4*)(bptr[f] + s * 32 + 4);
      size_t oa = abase + (size_t)f * 8192 + (size_t)s * 512;
      aH[f] = *(const bf16x8*)(whp + oa);
      aL[f] = *(const bf16x8*)(wlp + oa);
    }
#pragma unroll
    for (int f = 0; f < 4; ++f)
#pragma unroll
      for (int e = 0; e < 8; ++e) {
        float v = rB[f][e];
        u16 h = f2bf(v);
        bH[f][e] = (short)h;
        bL[f][e] = (short)f2bf(v - bf2f(h));
      }
    MFMA16(aH, bH)
    MFMA16(aL, bH)
    MFMA16(aH, bL)
  }

  // epilogue: bias add + split + direct fragment stores
  const int q4 = lane >> 4;
#pragma unroll
  for (int i = 0; i < 4; ++i) {
    const int hbase = col0 + wm * 64 + i * 16 + q4 * 4;
    float b0 = bias[hbase + 0], b1 = bias[hbase + 1];
    float b2 = bias[hbase + 2], b3 = bias[hbase + 3];
    const int lane16 = (lane & 15) + ((i & 1) * 2 + (q4 >> 1)) * 16;
    const int sub = (q4 & 1) * 4;
#pragma unroll
    for (int j = 0; j < 4; ++j) {
      const int frag = ((row0 + wn * 64 + j * 16) >> 4) * 16 +
                       ((col0 + wm * 64 + i * 16) >> 5);
      size_t base = (size_t)frag * 512 + (size_t)lane16 * 8 + sub;
      ushort4 hv, lv;
      float v;
      v = acc[i][j][0] + b0; hv.x = f2bf(v); lv.x = f2bf(v - bf2f(hv.x));
      v = acc[i][j][1] + b1; hv.y = f2bf(v); lv.y = f2bf(v - bf2f(hv.y));
      v = acc[i][j][2] + b2; hv.z = f2bf(v); lv.z = f2bf(v - bf2f(hv.z));
      v = acc[i][j][3] + b3; hv.w = f2bf(v); lv.w = f2bf(v - bf2f(hv.w));
      *(ushort4*)(ohi + base) = hv;
      *(ushort4*)(olo + base) = lv;
    }
  }
}

// ---------------------------------------------------------------------------
// K_t GEMM (lit @ varKw.T) via LDS-staged MFMA; tanh epilogue.
__global__ __launch_bounds__(256, 2) void ktu_kernel(
    const u16* __restrict__ lithi, const u16* __restrict__ litlo,
    const u16* __restrict__ wkhi, const u16* __restrict__ wklo,
    const float* __restrict__ tvec, const float* __restrict__ attnw,
    float* __restrict__ upart) {
  __shared__ __align__(16) u16 lds[2][4][8][512];
  const int t = threadIdx.x, lane = t & 63, wid = t >> 6;
  const int wn = wid & 1, wm = wid >> 1;
  const int row0 = blockIdx.x * 128;
  const int l8 = lane * 8;

  const u16* sa = (wid == 0) ? lithi : (wid == 1) ? litlo : (wid == 2) ? wkhi : wklo;
  const int rb = (wid < 2) ? (row0 >> 4) : (blockIdx.y * 8);
  const u16* sab = sa + (size_t)rb * 8192 + l8;

#define KSTAGE(buf, s)                                                        \
  _Pragma("unroll") for (int f_ = 0; f_ < 8; ++f_)                            \
    stage_frag(sab + (size_t)f_ * 8192 + (size_t)(s) * 512,                   \
               &lds[buf][wid][f_][0]);

  KSTAGE(0, 0)
  f32x4 acc[4][4] = {};
#pragma unroll
  for (int s = 0; s < 16; ++s) {
    __syncthreads();
    if (s < 15) { KSTAGE((s + 1) & 1, s + 1) }
    const int b = s & 1;
    bf16x8 aH[4], aL[4], bH[4], bL[4];
#pragma unroll
    for (int f = 0; f < 4; ++f) {
      aH[f] = *(const bf16x8*)&lds[b][0][wn * 4 + f][l8];
      aL[f] = *(const bf16x8*)&lds[b][1][wn * 4 + f][l8];
      bH[f] = *(const bf16x8*)&lds[b][2][wm * 4 + f][l8];
      bL[f] = *(const bf16x8*)&lds[b][3][wm * 4 + f][l8];
    }
    MFMAS(aH, aL, bH, bL);
  }
#undef KSTAGE

  const int cbase = blockIdx.y * 128 + wm * 64;
  float tv[4], aw[4];
#pragma unroll
  for (int j = 0; j < 4; ++j) {
    int c = cbase + j * 16 + (lane & 15);
    tv[j] = tvec[c]; aw[j] = attnw[c];
  }
  float us[4][4];
#pragma unroll
  for (int i = 0; i < 4; ++i)
#pragma unroll
    for (int r = 0; r < 4; ++r) {
      float s = 0.f;
#pragma unroll
      for (int j = 0; j < 4; ++j) {
        float x = acc[i][j][r] + tv[j];
        float th = 1.0f - 2.0f / (__expf(2.0f * x) + 1.0f);   // safe tanh
        s += th * aw[j];
      }
      us[i][r] = s;
    }
#pragma unroll
  for (int m = 1; m < 16; m <<= 1)
#pragma unroll
    for (int i = 0; i < 4; ++i)
#pragma unroll
      for (int r = 0; r < 4; ++r) us[i][r] += __shfl_xor(us[i][r], m, 64);
  if ((lane & 15) == 0) {
#pragma unroll
    for (int i = 0; i < 4; ++i)
#pragma unroll
      for (int r = 0; r < 4; ++r) {
        int row = row0 + wn * 64 + i * 16 + (lane >> 4) * 4 + r;
        upart[(size_t)(blockIdx.y * 2 + wm) * NVARS + row] = us[i][r];
      }
  }
}

// ---------------------------------------------------------------------------
// scores = q @ k.T / sqrt(H): LDS-staged 3-pass split MFMA + XCD supertile
// swizzle; masked max/argmax/sumexp epilogue.
__global__ __launch_bounds__(256, 2) void scores_kernel(
    const u16* __restrict__ qhi, const u16* __restrict__ qlo,
    const u16* __restrict__ khi, const u16* __restrict__ klo,
    const unsigned long long* __restrict__ vmask, SPart* __restrict__ parts) {
  __shared__ __align__(16) u16 lds[2][4][8][512];
  __shared__ unsigned long long mrow[128][2];
  __shared__ float s_rv[4]; __shared__ int s_ri[4]; __shared__ float s_rs[4];
  __shared__ float s_bm; __shared__ int s_ba;

  const int t = threadIdx.x;
  const int lane = t & 63;
  const int wid = t >> 6;
  const int wn = wid & 1, wm = wid >> 1;
  const int l8 = lane * 8;

  // XCD supertile swizzle (bijective on [0,1024))
  const int bid = blockIdx.x;
  const int xcd = bid & 7, p = bid >> 3;
  const int sp = p >> 6, q = p & 63;
  const int g = xcd * 2 + sp;
  const int bx = (g & 3) * 8 + (q & 7);
  const int by = (g >> 2) * 8 + (q >> 3);

  const int n0 = by * 128;
  const int m0 = bx * 128;

  const u16* sa = (wid == 0) ? qhi : (wid == 1) ? qlo : (wid == 2) ? khi : klo;
  const int rb = (wid < 2) ? (n0 >> 4) : (m0 >> 4);
  const u16* sab = sa + (size_t)rb * 8192 + l8;

#define SSTAGE(buf, s)                                                        \
  _Pragma("unroll") for (int f_ = 0; f_ < 8; ++f_)                            \
    stage_frag(sab + (size_t)f_ * 8192 + (size_t)(s) * 512,                   \
               &lds[buf][wid][f_][0]);

  {
    int r = t >> 1, w = t & 1;
    mrow[r][w] = vmask[(size_t)(n0 + r) * (NMS / 64) + (m0 >> 6) + w];
  }

  SSTAGE(0, 0)
  f32x4 acc[4][4] = {};
#pragma unroll
  for (int s = 0; s < 16; ++s) {
    __syncthreads();
    if (s < 15) { SSTAGE((s + 1) & 1, s + 1) }
    const int b = s & 1;
    bf16x8 aH[4], aL[4], bH[4], bL[4];
#pragma unroll
    for (int f = 0; f < 4; ++f) {
      aH[f] = *(const bf16x8*)&lds[b][0][wn * 4 + f][l8];
      aL[f] = *(const bf16x8*)&lds[b][1][wn * 4 + f][l8];
      bH[f] = *(const bf16x8*)&lds[b][2][wm * 4 + f][l8];
      bL[f] = *(const bf16x8*)&lds[b][3][wm * 4 + f][l8];
    }
    MFMAS(aH, aL, bH, bL);
  }
#undef SSTAGE

  // C/D layout: col = lane&15, row = (lane>>4)*4 + reg
  const int rbase = wn * 64 + (lane >> 4) * 4;
  const int cb15 = (lane & 15);

  float mv = NEGV; int mi = 0x7fffffff;
#pragma unroll
  for (int i = 0; i < 4; ++i) {
#pragma unroll
    for (int r = 0; r < 4; ++r) {
      int rl = rbase + i * 16 + r;
      unsigned long long ww = mrow[rl][wm];
      int gb = (n0 + rl) * NMS + m0;
#pragma unroll
      for (int j = 0; j < 4; ++j) {
        int bit = j * 16 + cb15;
        int cl = wm * 64 + bit;
        float sv = acc[i][j][r] * RSQRT_H;
        acc[i][j][r] = sv;
        bool valid = ((ww >> bit) & 1ull) != 0;
        if (valid && (sv > mv || (sv == mv && gb + cl < mi))) { mv = sv; mi = gb + cl; }
      }
    }
  }
  wreduce_maxidx(mv, mi);
  if ((t & 63) == 0) { s_rv[wid] = mv; s_ri[wid] = mi; }
  __syncthreads();
  if (t == 0) {
    float bm = s_rv[0]; int ba = s_ri[0];
    for (int w = 1; w < 4; ++w)
      if (s_rv[w] > bm || (s_rv[w] == bm && s_ri[w] < ba)) { bm = s_rv[w]; ba = s_ri[w]; }
    s_bm = bm; s_ba = ba;
  }
  __syncthreads();
  const float bm = s_bm;

  float se = 0.f;
#pragma unroll
  for (int i = 0; i < 4; ++i) {
#pragma unroll
    for (int r = 0; r < 4; ++r) {
      int rl = rbase + i * 16 + r;
      unsigned long long ww = mrow[rl][wm];
#pragma unroll
      for (int j = 0; j < 4; ++j) {
        int bit = j * 16 + cb15;
        bool valid = ((ww >> bit) & 1ull) != 0;
        if (valid) se += __expf(acc[i][j][r] - bm);
      }
    }
  }
  se = wreduce_sum(se);
  if ((t & 63) == 0) s_rs[wid] = se;
  __syncthreads();
  if (t == 0) {
    SPart pt;
    pt.m = s_bm;
    pt.s = s_rs[0] + s_rs[1] + s_rs[2] + s_rs[3];
    pt.a = s_ba; pt.pad = 0;
    parts[by * 32 + bx] = pt;
  }
}

// ---------------------------------------------------------------------------
// u reduction stage 1: 64 blocks x 256 vars -> per-block {max, argmax, sumexp}.
__global__ __launch_bounds__(256) void usum_kernel(
    const float* __restrict__ upart, SPart* __restrict__ uparts2) {
  __shared__ float s_rv[4]; __shared__ int s_ri[4]; __shared__ float s_rs[4];
  __shared__ float s_bm; __shared__ int s_ba;
  const int t = threadIdx.x;
  const int i = blockIdx.x * 256 + t;
  float u = 0.f;
#pragma unroll
  for (int p = 0; p < 8; ++p) u += upart[(size_t)p * NVARS + i];
  float mv = u; int mi = i;
  wreduce_maxidx(mv, mi);
  if ((t & 63) == 0) { s_rv[t >> 6] = mv; s_ri[t >> 6] = mi; }
  __syncthreads();
  if (t == 0) {
    float bm = s_rv[0]; int ba = s_ri[0];
    for (int w = 1; w < 4; ++w)
      if (s_rv[w] > bm || (s_rv[w] == bm && s_ri[w] < ba)) { bm = s_rv[w]; ba = s_ri[w]; }
    s_bm = bm; s_ba = ba;
  }
  __syncthreads();
  float se = __expf(u - s_bm);
  se = wreduce_sum(se);
  if ((t & 63) == 0) s_rs[t >> 6] = se;
  __syncthreads();
  if (t == 0) {
    SPart p;
    p.m = s_bm;
    p.s = s_rs[0] + s_rs[1] + s_rs[2] + s_rs[3];
    p.a = s_ba; p.pad = 0;
    uparts2[blockIdx.x] = p;
  }
}

// ---------------------------------------------------------------------------
// Final combine.  d_out is FLOAT32 x4: {c_logp, pos_idx[ci], neg_idx[cj], var_idx}.
__global__ __launch_bounds__(256) void final_kernel(
    const SPart* __restrict__ uparts2, const SPart* __restrict__ parts,
    const int* __restrict__ pos_idx, const int* __restrict__ neg_idx,
    float* __restrict__ out) {
  __shared__ float s_rv[4]; __shared__ int s_ri[4]; __shared__ float s_rs[4];
  __shared__ float s_umax; __shared__ int s_uarg; __shared__ float s_usum;
  __shared__ float s_gm; __shared__ int s_ga;
  const int t = threadIdx.x;

  // --- u parts (64) ---
  float mv = -3.0e38f; int mi = 0x7fffffff;
  SPart up;
  if (t < 64) {
    up = uparts2[t];
    mv = up.m; mi = up.a;
  }
  wreduce_maxidx(mv, mi);
  if ((t & 63) == 0) { s_rv[t >> 6] = mv; s_ri[t >> 6] = mi; }
  __syncthreads();
  if (t == 0) {
    float bm = s_rv[0]; int ba = s_ri[0];
    for (int w = 1; w < 4; ++w)
      if (s_rv[w] > bm || (s_rv[w] == bm && s_ri[w] < ba)) { bm = s_rv[w]; ba = s_ri[w]; }
    s_umax = bm; s_uarg = ba;
  }
  __syncthreads();
  float se = (t < 64) ? up.s * __expf(up.m - s_umax) : 0.f;
  se = wreduce_sum(se);
  if ((t & 63) == 0) s_rs[t >> 6] = se;
  __syncthreads();
  if (t == 0) s_usum = s_rs[0] + s_rs[1] + s_rs[2] + s_rs[3];
  __syncthreads();

  // --- score parts (1024) ---
  mv = NEGV; mi = 0x7fffffff;
  for (int i = t; i < 1024; i += 256) {
    SPart p = parts[i];
    if (p.m > mv || (p.m == mv && p.a < mi)) { mv = p.m; mi = p.a; }
  }
  wreduce_maxidx(mv, mi);
  if ((t & 63) == 0) { s_rv[t >> 6] = mv; s_ri[t >> 6] = mi; }
  __syncthreads();
  if (t == 0) {
    float bm = s_rv[0]; int ba = s_ri[0];
    for (int w = 1; w < 4; ++w)
      if (s_rv[w] > bm || (s_rv[w] == bm && s_ri[w] < ba)) { bm = s_rv[w]; ba = s_ri[w]; }
    s_gm = bm; s_ga = ba;
  }
  __syncthreads();
  const float gm = s_gm;
  float ss = 0.f;
  for (int i = t; i < 1024; i += 256) {
    SPart p = parts[i];
    ss += p.s * __expf(p.m - gm);
  }
  ss = wreduce_sum(ss);
  if ((t & 63) == 0) s_rs[t >> 6] = ss;
  __syncthreads();
  if (t == 0) {
    float gsum = s_rs[0] + s_rs[1] + s_rs[2] + s_rs[3];
    float c_logp = -logf(gsum) - logf(s_usum);
    int ga = s_ga;
    if (ga == 0x7fffffff) ga = 0;
    int ci = ga >> 12, cj = ga & 4095;
    out[0] = c_logp;
    out[1] = (float)pos_idx[ci];
    out[2] = (float)neg_idx[cj];
    out[3] = (float)s_uarg;
  }
}

extern "C" void kernel_launch(void* const* d_in, const int* in_sizes, int n_in,
                              void* d_out, int out_size, void* d_ws, size_t ws_size,
                              hipStream_t stream) {
  (void)in_sizes; (void)n_in; (void)out_size; (void)ws_size;
  const float* lit    = (const float*)d_in[0];
  const float* clause = (const float*)d_in[1];
  const int* pos_idx  = (const int*)d_in[2];
  const int* neg_idx  = (const int*)d_in[3];
  const void* keep    = d_in[4];
  const void* taken   = d_in[5];
  const float* varKw  = (const float*)d_in[6];
  const float* varKb  = (const float*)d_in[7];
  const float* varQw  = (const float*)d_in[8];
  const float* varQb  = (const float*)d_in[9];
  const float* attnw  = (const float*)d_in[10];
  // d_in[11] var_attn_b: uniform shift, cancels in log_softmax max/argmax
  const float* WQw    = (const float*)d_in[12];
  const float* WQb    = (const float*)d_in[13];
  const float* WKw    = (const float*)d_in[14];
  const float* WKb    = (const float*)d_in[15];

  char* ws = (char*)d_ws;
  size_t off = 0;
  auto alloc = [&](size_t b) {
    char* p = ws + off;
    off = (off + b + 255) & ~(size_t)255;
    return p;
  };
  double* qpart              = (double*)alloc((size_t)1024 * HH * 8);
  double* Qd                 = (double*)alloc(HH * 8);
  float* tvec                = (float*)alloc(HH * 4);
  float* upart               = (float*)alloc(8 * (size_t)NVARS * 4);
  unsigned long long* vmask  = (unsigned long long*)alloc((size_t)NPOS * (NMS / 64) * 8);
  u16* qhi                   = (u16*)alloc((size_t)NPOS * HH * 2);
  u16* qlo                   = (u16*)alloc((size_t)NPOS * HH * 2);
  u16* khi                   = (u16*)alloc((size_t)NMS * HH * 2);
  u16* klo                   = (u16*)alloc((size_t)NMS * HH * 2);
  u16* wkhi                  = (u16*)alloc((size_t)HH * HH * 2);
  u16* wklo                  = (u16*)alloc((size_t)HH * HH * 2);
  u16* pwqhi                 = (u16*)alloc((size_t)HH * HH * 2);
  u16* pwqlo                 = (u16*)alloc((size_t)HH * HH * 2);
  u16* pwkhi                 = (u16*)alloc((size_t)HH * HH * 2);
  u16* pwklo                 = (u16*)alloc((size_t)HH * HH * 2);
  u16* lithi                 = (u16*)alloc((size_t)NVARS * HH * 2);
  u16* litlo                 = (u16*)alloc((size_t)NVARS * HH * 2);
  SPart* parts               = (SPart*)alloc(1024 * sizeof(SPart));
  SPart* uparts2             = (SPart*)alloc(64 * sizeof(SPart));

  prep_kernel<<<21376, 256, 0, stream>>>(keep, taken, vmask, clause, qpart,
                                         lit, lithi, litlo,
                                         varKw, wkhi, wklo,
                                         WQw, pwqhi, pwqlo,
                                         WKw, pwkhi, pwklo);
  qred_kernel<<<32, 256, 0, stream>>>(qpart, Qd);
  prepmv_kernel<<<32, 256, 0, stream>>>(Qd, varQw, varQb, varKb, tvec);
  proj_kernel<<<dim3(32, 4, 2), 256, 0, stream>>>(clause, pos_idx, neg_idx,
                                                  pwqhi, pwqlo, pwkhi, pwklo,
                                                  WQb, WKb,
                                                  qhi, qlo, khi, klo);
  ktu_kernel<<<dim3(128, 4), 256, 0, stream>>>(lithi, litlo, wkhi, wklo,
                                               tvec, attnw, upart);
  scores_kernel<<<1024, 256, 0, stream>>>(qhi, qlo, khi, klo, vmask, parts);
  usum_kernel<<<64, 256, 0, stream>>>(upart, uparts2);
  final_kernel<<<1, 256, 0, stream>>>(uparts2, parts, pos_idx, neg_idx,
                                      (float*)d_out);
}